// Round 3
// baseline (790.134 us; speedup 1.0000x reference)
//
#include <hip/hip_runtime.h>

// ---------------------------------------------------------------------------
// GCN 2-layer forward: out = A_norm @ (drop(relu(A_norm @ (x W1) + b1)) W2) + b2
// A_norm = D^-1/2 (A + I) D^-1/2, deg from dst (+1 self loop).
// Dropout mask = JAX threefry, key(42), p=0.5.
// TF_VARIANT: 1 = partitionable 32-bit fold (bits1 ^ bits2)  <- this round
//             0 = partitionable out0 only (round-0: FAILED, absmax 0.405)
//             2 = partitionable out1 only
//             3 = legacy split-iota
// ---------------------------------------------------------------------------

#define TF_VARIANT 1

__device__ __forceinline__ unsigned tf_rotl(unsigned x, int d) {
    return (x << d) | (x >> (32 - d));
}

// Standard Threefry-2x32, 20 rounds, key = (0, 42) (= jax.random.key(42) data).
__device__ __forceinline__ void threefry2x32_k42(unsigned x0, unsigned x1,
                                                 unsigned& o0, unsigned& o1) {
    const unsigned K0 = 0u, K1 = 42u;
    const unsigned K2 = K0 ^ K1 ^ 0x1BD11BDAu;
    x0 += K0; x1 += K1;
#define TF_R(r) { x0 += x1; x1 = tf_rotl(x1, (r)); x1 ^= x0; }
    TF_R(13) TF_R(15) TF_R(26) TF_R(6)
    x0 += K1; x1 += K2 + 1u;
    TF_R(17) TF_R(29) TF_R(16) TF_R(24)
    x0 += K2; x1 += K0 + 2u;
    TF_R(13) TF_R(15) TF_R(26) TF_R(6)
    x0 += K0; x1 += K1 + 3u;
    TF_R(17) TF_R(29) TF_R(16) TF_R(24)
    x0 += K1; x1 += K2 + 4u;
    TF_R(13) TF_R(15) TF_R(26) TF_R(6)
    x0 += K2; x1 += K0 + 5u;
#undef TF_R
    o0 = x0; o1 = x1;
}

// keep = (uniform_bits < 2^31): top bit of the folded output word is 0.
__device__ __forceinline__ bool dropout_keep(unsigned flat_idx, unsigned total_half) {
    unsigned o0, o1;
#if TF_VARIANT == 0
    (void)total_half;
    threefry2x32_k42(0u, flat_idx, o0, o1);
    return (o0 & 0x80000000u) == 0u;
#elif TF_VARIANT == 1
    (void)total_half;
    threefry2x32_k42(0u, flat_idx, o0, o1);      // x = (hi(count)=0, lo(count)=i)
    return (((o0 ^ o1) >> 31) & 1u) == 0u;       // 32-bit fold: bits1 ^ bits2
#elif TF_VARIANT == 2
    (void)total_half;
    threefry2x32_k42(0u, flat_idx, o0, o1);
    return (o1 & 0x80000000u) == 0u;
#else
    if (flat_idx < total_half) {
        threefry2x32_k42(flat_idx, flat_idx + total_half, o0, o1);
        return (o0 & 0x80000000u) == 0u;
    } else {
        threefry2x32_k42(flat_idx - total_half, flat_idx, o0, o1);
        return (o1 & 0x80000000u) == 0u;
    }
#endif
}

// ---------------------------------------------------------------------------
// Edge-index element stride autodetect: int32 -> 1, int64 (little-endian) -> 2.
// Values are < 50000, so int64 hi-words are always 0; int32 words are uniform
// in [0, 50000) -> 8 odd-position words all zero has prob ~1e-37.
// ---------------------------------------------------------------------------
__global__ void detect_stride(const int* __restrict__ ei, unsigned* __restrict__ flag) {
    bool i64 = true;
    for (int k = 1; k <= 15; k += 2) i64 = i64 && (ei[k] == 0);
    *flag = i64 ? 2u : 1u;
}

// ---------------------------------------------------------------------------
// Y[nrows, NOUT] = X[nrows, K] @ W[K, NOUT]   (f32, LDS-staged rows)
// ---------------------------------------------------------------------------
template <int K, int NOUT, int ROWS, int RGROUPS>
__global__ __launch_bounds__(NOUT * RGROUPS)
void gemm_kernel(const float* __restrict__ X, const float* __restrict__ W,
                 float* __restrict__ Y, int nrows) {
    __shared__ float xs[ROWS][K];
    constexpr int NTH = NOUT * RGROUPS;
    constexpr int RPG = ROWS / RGROUPS;
    const int t = threadIdx.x;
    const int col = t % NOUT;
    const int rg = t / NOUT;
    const int row0 = blockIdx.x * ROWS;

    for (int i = t; i < ROWS * K; i += NTH) {
        int r = i / K, c = i % K;
        int gr = row0 + r;
        xs[r][c] = (gr < nrows) ? X[(size_t)gr * K + c] : 0.0f;
    }
    __syncthreads();

    float acc[RPG];
#pragma unroll
    for (int r = 0; r < RPG; ++r) acc[r] = 0.0f;

#pragma unroll 4
    for (int k = 0; k < K; ++k) {
        float w = W[k * NOUT + col];
#pragma unroll
        for (int r = 0; r < RPG; ++r)
            acc[r] += xs[rg * RPG + r][k] * w;
    }

#pragma unroll
    for (int r = 0; r < RPG; ++r) {
        int gr = row0 + rg * RPG + r;
        if (gr < nrows) Y[(size_t)gr * NOUT + col] = acc[r];
    }
}

__global__ void count_deg(const int* __restrict__ ei, const unsigned* __restrict__ flag,
                          unsigned* __restrict__ deg, int E) {
    int e = blockIdx.x * blockDim.x + threadIdx.x;
    if (e >= E) return;
    size_t st = *flag;
    int d = ei[((size_t)E + e) * st];  // dst
    atomicAdd(&deg[d], 1u);
}

__global__ void make_dinv(const unsigned* __restrict__ deg, float* __restrict__ dinv, int N) {
    int i = blockIdx.x * blockDim.x + threadIdx.x;
    if (i < N) dinv[i] = rsqrtf((float)(deg[i] + 1u));  // +1 = self loop
}

// out[i] = dinv[node]^2 * g[i] + b[f]   (self-loop term + bias; also un-poisons out)
template <int F>
__global__ void init_self(const float* __restrict__ g, const float* __restrict__ dinv,
                          const float* __restrict__ b, float* __restrict__ out, int total) {
    int i = blockIdx.x * blockDim.x + threadIdx.x;
    if (i >= total) return;
    int node = i / F;
    int f = i % F;
    float dn = dinv[node];
    out[i] = dn * dn * g[i] + b[f];
}

// out[dst] += dinv[src]*dinv[dst] * h[src]  over all edges (atomic)
template <int F>
__global__ __launch_bounds__(256)
void scatter_edges(const float* __restrict__ h, const int* __restrict__ ei,
                   const unsigned* __restrict__ flag, const float* __restrict__ dinv,
                   float* __restrict__ out, int E) {
    constexpr int EPB = 256 / F;
    int e = blockIdx.x * EPB + threadIdx.x / F;
    int f = threadIdx.x % F;
    if (e >= E) return;
    size_t st = *flag;
    int s = ei[(size_t)e * st];              // src
    int d = ei[((size_t)E + e) * st];        // dst
    float nrm = dinv[s] * dinv[d];
    atomicAdd(&out[(size_t)d * F + f], nrm * h[(size_t)s * F + f]);
}

// h2 = dropout(relu(out1)) with exact JAX threefry mask
__global__ void relu_dropout(const float* __restrict__ out1, float* __restrict__ h2,
                             int total) {
    int i = blockIdx.x * blockDim.x + threadIdx.x;
    if (i >= total) return;
    float v = fmaxf(out1[i], 0.0f);
    bool keep = dropout_keep((unsigned)i, (unsigned)(total / 2));
    h2[i] = keep ? 2.0f * v : 0.0f;
}

extern "C" void kernel_launch(void* const* d_in, const int* in_sizes, int n_in,
                              void* d_out, int out_size, void* d_ws, size_t ws_size,
                              hipStream_t stream) {
    const float* x  = (const float*)d_in[0];
    const int*   ei = (const int*)d_in[1];
    const float* W1 = (const float*)d_in[2];
    const float* b1 = (const float*)d_in[3];
    const float* W2 = (const float*)d_in[4];
    const float* b2 = (const float*)d_in[5];
    float* out = (float*)d_out;

    const int Fdim = 256, Hdim = 128, Cdim = 64;
    const int N = in_sizes[0] / Fdim;   // 50000
    const int E = in_sizes[1] / 2;      // 800000 (element count is dtype-agnostic)

    // workspace layout (f32): h1[N*H] | out1[N*H] | g[N*C] | deg[N] | dinv[N] | flag
    float* h1     = (float*)d_ws;
    float* out1   = h1 + (size_t)N * Hdim;
    float* g      = out1 + (size_t)N * Hdim;
    unsigned* deg = (unsigned*)(g + (size_t)N * Cdim);
    float* dinv   = (float*)(deg + N);
    unsigned* flag = (unsigned*)(dinv + N);
    float* h2     = h1;  // h1 dead after scatter1 -> reuse

    hipMemsetAsync(deg, 0, (size_t)N * sizeof(unsigned), stream);

    detect_stride<<<1, 1, 0, stream>>>(ei, flag);

    // degree / dinv
    count_deg<<<(E + 255) / 256, 256, 0, stream>>>(ei, flag, deg, E);
    make_dinv<<<(N + 255) / 256, 256, 0, stream>>>(deg, dinv, N);

    // layer 1: h1 = x @ W1
    gemm_kernel<256, 128, 32, 2><<<(N + 31) / 32, 256, 0, stream>>>(x, W1, h1, N);
    // out1 = dinv^2 * h1 + b1 (self loop), then += edge messages
    init_self<128><<<((N * Hdim) + 255) / 256, 256, 0, stream>>>(h1, dinv, b1, out1, N * Hdim);
    scatter_edges<128><<<(E + 1) / 2, 256, 0, stream>>>(h1, ei, flag, dinv, out1, E);
    // h2 = dropout(relu(out1))
    relu_dropout<<<((N * Hdim) + 255) / 256, 256, 0, stream>>>(out1, h2, N * Hdim);

    // layer 2: g = h2 @ W2
    gemm_kernel<128, 64, 32, 4><<<(N + 31) / 32, 256, 0, stream>>>(h2, W2, g, N);
    init_self<64><<<((N * Cdim) + 255) / 256, 256, 0, stream>>>(g, dinv, b2, out, N * Cdim);
    scatter_edges<64><<<(E + 3) / 4, 256, 0, stream>>>(g, ei, flag, dinv, out, E);
}

// Round 4
// 526.631 us; speedup vs baseline: 1.5004x; 1.5004x over previous
//
#include <hip/hip_runtime.h>

// ---------------------------------------------------------------------------
// GCN 2-layer forward: out = A_norm @ (drop(relu(A_norm @ (x W1) + b1)) W2) + b2
// A_norm = D^-1/2 (A+I) D^-1/2.  CSR-gather formulation (no f32 atomics):
//   hs = dinv ⊙ (X @ W)          (GEMM epilogue scale)
//   out[i] = dinv[i]*(hs[i] + Σ_{j∈in(i)} hs[j]) + b
// Dropout mask = JAX threefry2x32, key(42), partitionable fold (o0^o1), p=0.5.
//   (variant verified round 3: absmax 9.8e-4)
// ---------------------------------------------------------------------------

__device__ __forceinline__ unsigned tf_rotl(unsigned x, int d) {
    return (x << d) | (x >> (32 - d));
}

__device__ __forceinline__ bool dropout_keep(unsigned flat_idx) {
    const unsigned K0 = 0u, K1 = 42u;
    const unsigned K2 = K0 ^ K1 ^ 0x1BD11BDAu;
    unsigned x0 = 0u, x1 = flat_idx;
    x0 += K0; x1 += K1;
#define TF_R(r) { x0 += x1; x1 = tf_rotl(x1, (r)); x1 ^= x0; }
    TF_R(13) TF_R(15) TF_R(26) TF_R(6)
    x0 += K1; x1 += K2 + 1u;
    TF_R(17) TF_R(29) TF_R(16) TF_R(24)
    x0 += K2; x1 += K0 + 2u;
    TF_R(13) TF_R(15) TF_R(26) TF_R(6)
    x0 += K0; x1 += K1 + 3u;
    TF_R(17) TF_R(29) TF_R(16) TF_R(24)
    x0 += K1; x1 += K2 + 4u;
    TF_R(13) TF_R(15) TF_R(26) TF_R(6)
    x0 += K2; x1 += K0 + 5u;
#undef TF_R
    return (((x0 ^ x1) >> 31) & 1u) == 0u;   // fold bits1^bits2, keep if < 2^31
}

// int32 vs int64 edge-index autodetect (values < 50000 -> i64 hi words are 0)
__global__ void detect_stride(const int* __restrict__ ei, unsigned* __restrict__ flag) {
    bool i64 = true;
    for (int k = 1; k <= 15; k += 2) i64 = i64 && (ei[k] == 0);
    *flag = i64 ? 2u : 1u;
}

__global__ void count_deg(const int* __restrict__ ei, const unsigned* __restrict__ flag,
                          unsigned* __restrict__ deg, int E) {
    int e = blockIdx.x * blockDim.x + threadIdx.x;
    if (e >= E) return;
    size_t st = *flag;
    atomicAdd(&deg[ei[((size_t)E + e) * st]], 1u);
}

__global__ void make_dinv(const unsigned* __restrict__ deg, float* __restrict__ dinv, int N) {
    int i = blockIdx.x * blockDim.x + threadIdx.x;
    if (i < N) dinv[i] = rsqrtf((float)(deg[i] + 1u));  // +1 = self loop
}

// single-block exclusive scan: rowptr[0..N] from deg[0..N-1]
__global__ __launch_bounds__(1024)
void scan_deg(const unsigned* __restrict__ deg, unsigned* __restrict__ rowptr, int N) {
    __shared__ unsigned part[1024];
    const int t = threadIdx.x;
    const int chunk = (N + 1023) / 1024;
    const int lo = t * chunk;
    const int hi = min(lo + chunk, N);
    unsigned s = 0;
    for (int i = lo; i < hi; ++i) s += deg[i];
    part[t] = s;
    __syncthreads();
    for (int off = 1; off < 1024; off <<= 1) {
        unsigned v = (t >= off) ? part[t - off] : 0u;
        __syncthreads();
        part[t] += v;
        __syncthreads();
    }
    unsigned run = (t == 0) ? 0u : part[t - 1];
    for (int i = lo; i < hi; ++i) { rowptr[i] = run; run += deg[i]; }
    if (lo < N && hi == N) rowptr[N] = run;  // thread owning the tail writes total
}

__global__ void fill_csr(const int* __restrict__ ei, const unsigned* __restrict__ flag,
                         const unsigned* __restrict__ rowptr, unsigned* __restrict__ cursor,
                         int* __restrict__ csr, int E) {
    int e = blockIdx.x * blockDim.x + threadIdx.x;
    if (e >= E) return;
    size_t st = *flag;
    int s = ei[(size_t)e * st];
    int d = ei[((size_t)E + e) * st];
    unsigned pos = atomicAdd(&cursor[d], 1u);
    csr[rowptr[d] + pos] = s;
}

// ---------------------------------------------------------------------------
// Y[r, NOUT] = scale[r] * (X[r, :] @ W)    (f32, LDS-staged rows)
// ---------------------------------------------------------------------------
template <int K, int NOUT, int ROWS, int RGROUPS>
__global__ __launch_bounds__(NOUT * RGROUPS)
void gemm_scaled(const float* __restrict__ X, const float* __restrict__ W,
                 const float* __restrict__ scale, float* __restrict__ Y, int nrows) {
    __shared__ float xs[ROWS][K];
    constexpr int NTH = NOUT * RGROUPS;
    constexpr int RPG = ROWS / RGROUPS;
    const int t = threadIdx.x;
    const int col = t % NOUT;
    const int rg = t / NOUT;
    const int row0 = blockIdx.x * ROWS;

    for (int i = t; i < ROWS * K; i += NTH) {
        int r = i / K, c = i % K;
        int gr = row0 + r;
        xs[r][c] = (gr < nrows) ? X[(size_t)gr * K + c] : 0.0f;
    }
    __syncthreads();

    float acc[RPG];
#pragma unroll
    for (int r = 0; r < RPG; ++r) acc[r] = 0.0f;

#pragma unroll 4
    for (int k = 0; k < K; ++k) {
        float w = W[k * NOUT + col];
#pragma unroll
        for (int r = 0; r < RPG; ++r)
            acc[r] += xs[rg * RPG + r][k] * w;
    }

#pragma unroll
    for (int r = 0; r < RPG; ++r) {
        int gr = row0 + rg * RPG + r;
        if (gr < nrows) Y[(size_t)gr * NOUT + col] = acc[r] * scale[gr];
    }
}

// ---------------------------------------------------------------------------
// Gather: one wave per node. out[i] = dinv[i]*(hs[i] + sum_in hs[j]) + b
// F=128: float2 per lane; DROP applies relu+jax-dropout (flat idx = node*F+f).
// ---------------------------------------------------------------------------
template <int F, bool DROP>
__global__ __launch_bounds__(256)
void gather_nodes(const float* __restrict__ hs, const int* __restrict__ csr,
                  const unsigned* __restrict__ rowptr, const float* __restrict__ dinv,
                  const float* __restrict__ bias, float* __restrict__ outp, int N) {
    const int node = blockIdx.x * 4 + (threadIdx.x >> 6);
    if (node >= N) return;
    const int lane = threadIdx.x & 63;
    const unsigned beg = rowptr[node];
    const unsigned end = rowptr[node + 1];
    const float dn = dinv[node];

    if (F == 128) {
        const float2* hp = (const float2*)hs;
        float2 acc = hp[(size_t)node * 64 + lane];
        for (unsigned k = beg; k < end; ++k) {
            int j = csr[k];
            float2 v = hp[(size_t)j * 64 + lane];
            acc.x += v.x; acc.y += v.y;
        }
        const int f0 = 2 * lane;
        float o0 = dn * acc.x + bias[f0];
        float o1 = dn * acc.y + bias[f0 + 1];
        if (DROP) {
            o0 = fmaxf(o0, 0.0f); o1 = fmaxf(o1, 0.0f);
            unsigned base = (unsigned)node * 128u + (unsigned)f0;
            o0 = dropout_keep(base) ? 2.0f * o0 : 0.0f;
            o1 = dropout_keep(base + 1u) ? 2.0f * o1 : 0.0f;
        }
        ((float2*)outp)[(size_t)node * 64 + lane] = make_float2(o0, o1);
    } else {  // F == 64
        float acc = hs[(size_t)node * 64 + lane];
        for (unsigned k = beg; k < end; ++k) {
            int j = csr[k];
            acc += hs[(size_t)j * 64 + lane];
        }
        outp[(size_t)node * 64 + lane] = dn * acc + bias[lane];
    }
}

extern "C" void kernel_launch(void* const* d_in, const int* in_sizes, int n_in,
                              void* d_out, int out_size, void* d_ws, size_t ws_size,
                              hipStream_t stream) {
    const float* x  = (const float*)d_in[0];
    const int*   ei = (const int*)d_in[1];
    const float* W1 = (const float*)d_in[2];
    const float* b1 = (const float*)d_in[3];
    const float* W2 = (const float*)d_in[4];
    const float* b2 = (const float*)d_in[5];
    float* out = (float*)d_out;

    const int Fdim = 256, Hdim = 128, Cdim = 64;
    const int N = in_sizes[0] / Fdim;   // 50000
    const int E = in_sizes[1] / 2;      // 800000

    // workspace (f32 units): buffA[N*128] | buffB[N*128] | deg[N] | cursor[N] |
    //                        dinv[N] | rowptr[N+1] | csr[E] | flag
    float* buffA = (float*)d_ws;                         // h1s, then gs (reuse)
    float* buffB = buffA + (size_t)N * Hdim;             // h2
    unsigned* deg    = (unsigned*)(buffB + (size_t)N * Hdim);
    unsigned* cursor = deg + N;
    float*    dinv   = (float*)(cursor + N);
    unsigned* rowptr = (unsigned*)(dinv + N);
    int*      csr    = (int*)(rowptr + (N + 1));
    unsigned* flag   = (unsigned*)(csr + E);

    // zero deg + cursor in one shot (adjacent)
    hipMemsetAsync(deg, 0, 2 * (size_t)N * sizeof(unsigned), stream);

    detect_stride<<<1, 1, 0, stream>>>(ei, flag);
    count_deg<<<(E + 255) / 256, 256, 0, stream>>>(ei, flag, deg, E);
    make_dinv<<<(N + 255) / 256, 256, 0, stream>>>(deg, dinv, N);
    scan_deg<<<1, 1024, 0, stream>>>(deg, rowptr, N);
    fill_csr<<<(E + 255) / 256, 256, 0, stream>>>(ei, flag, rowptr, cursor, csr, E);

    // layer 1: buffA = dinv ⊙ (x @ W1); buffB = drop(relu(gather(buffA)))
    gemm_scaled<256, 128, 32, 2><<<(N + 31) / 32, 256, 0, stream>>>(x, W1, dinv, buffA, N);
    gather_nodes<128, true><<<(N + 3) / 4, 256, 0, stream>>>(buffA, csr, rowptr, dinv, b1, buffB, N);

    // layer 2: buffA = dinv ⊙ (buffB @ W2); out = gather(buffA) + b2
    gemm_scaled<128, 64, 32, 4><<<(N + 31) / 32, 256, 0, stream>>>(buffB, W2, dinv, buffA, N);
    gather_nodes<64, false><<<(N + 3) / 4, 256, 0, stream>>>(buffA, csr, rowptr, dinv, b2, out, N);
}

// Round 5
// 448.802 us; speedup vs baseline: 1.7605x; 1.1734x over previous
//
#include <hip/hip_runtime.h>

// ---------------------------------------------------------------------------
// GCN 2-layer forward: out = A_norm @ (drop(relu(A_norm @ (x W1) + b1)) W2) + b2
// A_norm = D^-1/2 (A+I) D^-1/2.  CSR-gather formulation (no f32 atomics):
//   hs = dinv ⊙ (X @ W)          (GEMM epilogue scale)
//   out[i] = dinv[i]*(hs[i] + Σ_{j∈in(i)} hs[j]) + b
// GEMMs: split-bf16 MFMA (hi/lo, 3 MFMA per tile) — fp32-class accuracy.
// Dropout mask = JAX threefry2x32, key(42), partitionable fold (o0^o1), p=0.5.
//   (verified round 3/4: absmax ~1e-3)
// ---------------------------------------------------------------------------

typedef __attribute__((ext_vector_type(8))) short bf16x8;   // 8 bf16 in 4 VGPRs
typedef __attribute__((ext_vector_type(4))) float f32x4;    // MFMA C/D

__device__ __forceinline__ unsigned tf_rotl(unsigned x, int d) {
    return (x << d) | (x >> (32 - d));
}

__device__ __forceinline__ bool dropout_keep(unsigned flat_idx) {
    const unsigned K0 = 0u, K1 = 42u;
    const unsigned K2 = K0 ^ K1 ^ 0x1BD11BDAu;
    unsigned x0 = 0u, x1 = flat_idx;
    x0 += K0; x1 += K1;
#define TF_R(r) { x0 += x1; x1 = tf_rotl(x1, (r)); x1 ^= x0; }
    TF_R(13) TF_R(15) TF_R(26) TF_R(6)
    x0 += K1; x1 += K2 + 1u;
    TF_R(17) TF_R(29) TF_R(16) TF_R(24)
    x0 += K2; x1 += K0 + 2u;
    TF_R(13) TF_R(15) TF_R(26) TF_R(6)
    x0 += K0; x1 += K1 + 3u;
    TF_R(17) TF_R(29) TF_R(16) TF_R(24)
    x0 += K1; x1 += K2 + 4u;
    TF_R(13) TF_R(15) TF_R(26) TF_R(6)
    x0 += K2; x1 += K0 + 5u;
#undef TF_R
    return (((x0 ^ x1) >> 31) & 1u) == 0u;   // fold bits1^bits2, keep if < 2^31
}

// ---- split-bf16 helpers ----------------------------------------------------
__device__ __forceinline__ unsigned short bf16_rn(float x) {
    unsigned u = __float_as_uint(x);
    unsigned r = u + 0x7FFFu + ((u >> 16) & 1u);
    return (unsigned short)(r >> 16);
}
__device__ __forceinline__ void split_bf16(float x, unsigned short& h, unsigned short& l) {
    h = bf16_rn(x);
    float fh = __uint_as_float(((unsigned)h) << 16);
    l = bf16_rn(x - fh);
}
__device__ __forceinline__ void split4(float4 v, ushort4& h, ushort4& l) {
    unsigned short h0, h1, h2, h3, l0, l1, l2, l3;
    split_bf16(v.x, h0, l0); split_bf16(v.y, h1, l1);
    split_bf16(v.z, h2, l2); split_bf16(v.w, h3, l3);
    h = make_ushort4(h0, h1, h2, h3);
    l = make_ushort4(l0, l1, l2, l3);
}

// int32 vs int64 edge-index autodetect (values < 50000 -> i64 hi words are 0)
__global__ void detect_stride(const int* __restrict__ ei, unsigned* __restrict__ flag) {
    bool i64 = true;
    for (int k = 1; k <= 15; k += 2) i64 = i64 && (ei[k] == 0);
    *flag = i64 ? 2u : 1u;
}

__global__ void count_deg(const int* __restrict__ ei, const unsigned* __restrict__ flag,
                          unsigned* __restrict__ deg, int E) {
    int e = blockIdx.x * blockDim.x + threadIdx.x;
    if (e >= E) return;
    size_t st = *flag;
    atomicAdd(&deg[ei[((size_t)E + e) * st]], 1u);
}

__global__ void make_dinv(const unsigned* __restrict__ deg, float* __restrict__ dinv, int N) {
    int i = blockIdx.x * blockDim.x + threadIdx.x;
    if (i < N) dinv[i] = rsqrtf((float)(deg[i] + 1u));  // +1 = self loop
}

// single-block exclusive scan: rowptr[0..N] from deg[0..N-1]
__global__ __launch_bounds__(1024)
void scan_deg(const unsigned* __restrict__ deg, unsigned* __restrict__ rowptr, int N) {
    __shared__ unsigned part[1024];
    const int t = threadIdx.x;
    const int chunk = (N + 1023) / 1024;
    const int lo = t * chunk;
    const int hi = min(lo + chunk, N);
    unsigned s = 0;
    for (int i = lo; i < hi; ++i) s += deg[i];
    part[t] = s;
    __syncthreads();
    for (int off = 1; off < 1024; off <<= 1) {
        unsigned v = (t >= off) ? part[t - off] : 0u;
        __syncthreads();
        part[t] += v;
        __syncthreads();
    }
    unsigned run = (t == 0) ? 0u : part[t - 1];
    for (int i = lo; i < hi; ++i) { rowptr[i] = run; run += deg[i]; }
    if (lo < N && hi == N) rowptr[N] = run;
}

__global__ void fill_csr(const int* __restrict__ ei, const unsigned* __restrict__ flag,
                         const unsigned* __restrict__ rowptr, unsigned* __restrict__ cursor,
                         int* __restrict__ csr, int E) {
    int e = blockIdx.x * blockDim.x + threadIdx.x;
    if (e >= E) return;
    size_t st = *flag;
    int s = ei[(size_t)e * st];
    int d = ei[((size_t)E + e) * st];
    unsigned pos = atomicAdd(&cursor[d], 1u);
    csr[rowptr[d] + pos] = s;
}

// ---------------------------------------------------------------------------
// Prep: wT_hi/lo[n*K + k] = split_bf16(W[k*NOUT + n])   (one-time, tiny)
// ---------------------------------------------------------------------------
__global__ void split_wT(const float* __restrict__ W, unsigned short* __restrict__ wT_hi,
                         unsigned short* __restrict__ wT_lo, int K, int NOUT) {
    int idx = blockIdx.x * blockDim.x + threadIdx.x;
    if (idx >= K * NOUT) return;
    int k = idx / NOUT, n = idx % NOUT;
    unsigned short h, l;
    split_bf16(W[idx], h, l);
    wT_hi[(size_t)n * K + k] = h;
    wT_lo[(size_t)n * K + k] = l;
}

// ---------------------------------------------------------------------------
// Y[r, NOUT_] = scale[r] * (X[r, :] @ W)  via split-bf16 MFMA 16x16x32.
// Block: 256 threads (4 waves), BM=64 rows, BK=32 k-step.
// Wave owns all 4 row-tiles x CT col-tiles (CT = NOUT_/64).
// A frag: lane l -> A[l&15][(l>>4)*8 + j]; B frag from wT: contiguous k.
// D: row=(l>>4)*4+j, col=l&15  (m89-verified).
// ---------------------------------------------------------------------------
template <int K_, int NOUT_>
__global__ __launch_bounds__(256)
void gemm_mfma(const float* __restrict__ X, const unsigned short* __restrict__ wT_hi,
               const unsigned short* __restrict__ wT_lo, const float* __restrict__ scale,
               float* __restrict__ Y, int nrows) {
    constexpr int BM = 64, BK = 32, NKT = K_ / BK;
    constexpr int CT = NOUT_ / 64;            // col-tiles per wave
    constexpr int LDW = BK + 8;               // +8 bf16 pad: row stride 80B (16B-mult)
    constexpr int WPT = NOUT_ * 8 / 256;      // ushort4 per thread per half (W staging)

    __shared__ __attribute__((aligned(16))) unsigned short xs_hi[BM][LDW];
    __shared__ __attribute__((aligned(16))) unsigned short xs_lo[BM][LDW];
    __shared__ __attribute__((aligned(16))) unsigned short ws_hi[NOUT_][LDW];
    __shared__ __attribute__((aligned(16))) unsigned short ws_lo[NOUT_][LDW];

    const int t = threadIdx.x;
    const int wave = t >> 6, lane = t & 63;
    const int m16 = lane & 15, kg = lane >> 4;
    const int row0 = blockIdx.x * BM;
    const int n0 = wave * (16 * CT);

    f32x4 acc[4][CT];
#pragma unroll
    for (int r = 0; r < 4; ++r)
#pragma unroll
        for (int c = 0; c < CT; ++c) acc[r][c] = {0.f, 0.f, 0.f, 0.f};

    float4 xpre[2];
    ushort4 wpre_h[WPT], wpre_l[WPT];

    // prefetch K-step 0
#pragma unroll
    for (int i = 0; i < 2; ++i) {
        int idx = t + i * 256;
        int r = idx >> 3, c4 = idx & 7;
        int gr = row0 + r;
        xpre[i] = (gr < nrows) ? *(const float4*)&X[(size_t)gr * K_ + c4 * 4]
                               : make_float4(0.f, 0.f, 0.f, 0.f);
    }
#pragma unroll
    for (int i = 0; i < WPT; ++i) {
        int idx = t + i * 256;
        int n = idx >> 3, c4 = idx & 7;
        wpre_h[i] = *(const ushort4*)&wT_hi[(size_t)n * K_ + c4 * 4];
        wpre_l[i] = *(const ushort4*)&wT_lo[(size_t)n * K_ + c4 * 4];
    }

    for (int kb = 0; kb < NKT; ++kb) {
        // stage prefetched regs -> LDS (split x on the fly)
#pragma unroll
        for (int i = 0; i < 2; ++i) {
            int idx = t + i * 256;
            int r = idx >> 3, c4 = idx & 7;
            ushort4 h, l;
            split4(xpre[i], h, l);
            *(ushort4*)&xs_hi[r][c4 * 4] = h;
            *(ushort4*)&xs_lo[r][c4 * 4] = l;
        }
#pragma unroll
        for (int i = 0; i < WPT; ++i) {
            int idx = t + i * 256;
            int n = idx >> 3, c4 = idx & 7;
            *(ushort4*)&ws_hi[n][c4 * 4] = wpre_h[i];
            *(ushort4*)&ws_lo[n][c4 * 4] = wpre_l[i];
        }
        __syncthreads();

        // issue next K-step's global loads (hide HBM under MFMA)
        if (kb + 1 < NKT) {
            const int koff = (kb + 1) * BK;
#pragma unroll
            for (int i = 0; i < 2; ++i) {
                int idx = t + i * 256;
                int r = idx >> 3, c4 = idx & 7;
                int gr = row0 + r;
                xpre[i] = (gr < nrows) ? *(const float4*)&X[(size_t)gr * K_ + koff + c4 * 4]
                                       : make_float4(0.f, 0.f, 0.f, 0.f);
            }
#pragma unroll
            for (int i = 0; i < WPT; ++i) {
                int idx = t + i * 256;
                int n = idx >> 3, c4 = idx & 7;
                wpre_h[i] = *(const ushort4*)&wT_hi[(size_t)n * K_ + koff + c4 * 4];
                wpre_l[i] = *(const ushort4*)&wT_lo[(size_t)n * K_ + koff + c4 * 4];
            }
        }

        // compute on LDS tiles
        bf16x8 bh[CT], bl[CT];
#pragma unroll
        for (int c = 0; c < CT; ++c) {
            bh[c] = *(const bf16x8*)&ws_hi[n0 + c * 16 + m16][kg * 8];
            bl[c] = *(const bf16x8*)&ws_lo[n0 + c * 16 + m16][kg * 8];
        }
#pragma unroll
        for (int r = 0; r < 4; ++r) {
            bf16x8 ah = *(const bf16x8*)&xs_hi[r * 16 + m16][kg * 8];
            bf16x8 al = *(const bf16x8*)&xs_lo[r * 16 + m16][kg * 8];
#pragma unroll
            for (int c = 0; c < CT; ++c) {
                acc[r][c] = __builtin_amdgcn_mfma_f32_16x16x32_bf16(ah, bh[c], acc[r][c], 0, 0, 0);
                acc[r][c] = __builtin_amdgcn_mfma_f32_16x16x32_bf16(ah, bl[c], acc[r][c], 0, 0, 0);
                acc[r][c] = __builtin_amdgcn_mfma_f32_16x16x32_bf16(al, bh[c], acc[r][c], 0, 0, 0);
            }
        }
        __syncthreads();
    }

    // epilogue: scale rows by dinv and store
#pragma unroll
    for (int r = 0; r < 4; ++r) {
#pragma unroll
        for (int j = 0; j < 4; ++j) {
            int gr = row0 + r * 16 + kg * 4 + j;
            if (gr < nrows) {
                float s = scale[gr];
#pragma unroll
                for (int c = 0; c < CT; ++c)
                    Y[(size_t)gr * NOUT_ + n0 + c * 16 + m16] = acc[r][c][j] * s;
            }
        }
    }
}

// ---------------------------------------------------------------------------
// Gather: one wave per node. out[i] = dinv[i]*(hs[i] + sum_in hs[j]) + b
// ---------------------------------------------------------------------------
template <int F, bool DROP>
__global__ __launch_bounds__(256)
void gather_nodes(const float* __restrict__ hs, const int* __restrict__ csr,
                  const unsigned* __restrict__ rowptr, const float* __restrict__ dinv,
                  const float* __restrict__ bias, float* __restrict__ outp, int N) {
    const int node = blockIdx.x * 4 + (threadIdx.x >> 6);
    if (node >= N) return;
    const int lane = threadIdx.x & 63;
    const unsigned beg = rowptr[node];
    const unsigned end = rowptr[node + 1];
    const float dn = dinv[node];

    if (F == 128) {
        const float2* hp = (const float2*)hs;
        float2 acc = hp[(size_t)node * 64 + lane];
        for (unsigned k = beg; k < end; ++k) {
            int j = csr[k];
            float2 v = hp[(size_t)j * 64 + lane];
            acc.x += v.x; acc.y += v.y;
        }
        const int f0 = 2 * lane;
        float o0 = dn * acc.x + bias[f0];
        float o1 = dn * acc.y + bias[f0 + 1];
        if (DROP) {
            o0 = fmaxf(o0, 0.0f); o1 = fmaxf(o1, 0.0f);
            unsigned base = (unsigned)node * 128u + (unsigned)f0;
            o0 = dropout_keep(base) ? 2.0f * o0 : 0.0f;
            o1 = dropout_keep(base + 1u) ? 2.0f * o1 : 0.0f;
        }
        ((float2*)outp)[(size_t)node * 64 + lane] = make_float2(o0, o1);
    } else {  // F == 64
        float acc = hs[(size_t)node * 64 + lane];
        for (unsigned k = beg; k < end; ++k) {
            int j = csr[k];
            acc += hs[(size_t)j * 64 + lane];
        }
        outp[(size_t)node * 64 + lane] = dn * acc + bias[lane];
    }
}

extern "C" void kernel_launch(void* const* d_in, const int* in_sizes, int n_in,
                              void* d_out, int out_size, void* d_ws, size_t ws_size,
                              hipStream_t stream) {
    const float* x  = (const float*)d_in[0];
    const int*   ei = (const int*)d_in[1];
    const float* W1 = (const float*)d_in[2];
    const float* b1 = (const float*)d_in[3];
    const float* W2 = (const float*)d_in[4];
    const float* b2 = (const float*)d_in[5];
    float* out = (float*)d_out;

    const int Fdim = 256, Hdim = 128, Cdim = 64;
    const int N = in_sizes[0] / Fdim;   // 50000
    const int E = in_sizes[1] / 2;      // 800000

    // workspace: wT1_hi|wT1_lo (256*128 us) | wT2_hi|wT2_lo (128*64 us) |
    //            buffA[N*128] f32 | buffB[N*128] f32 | deg[N] | cursor[N] |
    //            dinv[N] | rowptr[N+1] | csr[E] | flag
    unsigned short* wT1_hi = (unsigned short*)d_ws;
    unsigned short* wT1_lo = wT1_hi + 256 * 128;
    unsigned short* wT2_hi = wT1_lo + 256 * 128;
    unsigned short* wT2_lo = wT2_hi + 128 * 64;
    float* buffA = (float*)(wT2_lo + 128 * 64);          // 160KB offset, 16B-aligned
    float* buffB = buffA + (size_t)N * Hdim;
    unsigned* deg    = (unsigned*)(buffB + (size_t)N * Hdim);
    unsigned* cursor = deg + N;
    float*    dinv   = (float*)(cursor + N);
    unsigned* rowptr = (unsigned*)(dinv + N);
    int*      csr    = (int*)(rowptr + (N + 1));
    unsigned* flag   = (unsigned*)(csr + E);

    hipMemsetAsync(deg, 0, 2 * (size_t)N * sizeof(unsigned), stream);

    detect_stride<<<1, 1, 0, stream>>>(ei, flag);
    count_deg<<<(E + 255) / 256, 256, 0, stream>>>(ei, flag, deg, E);
    make_dinv<<<(N + 255) / 256, 256, 0, stream>>>(deg, dinv, N);
    scan_deg<<<1, 1024, 0, stream>>>(deg, rowptr, N);
    fill_csr<<<(E + 255) / 256, 256, 0, stream>>>(ei, flag, rowptr, cursor, csr, E);

    split_wT<<<(256 * 128 + 255) / 256, 256, 0, stream>>>(W1, wT1_hi, wT1_lo, 256, 128);
    split_wT<<<(128 * 64 + 255) / 256, 256, 0, stream>>>(W2, wT2_hi, wT2_lo, 128, 64);

    // layer 1: buffA = dinv ⊙ (x @ W1); buffB = drop(relu(gather(buffA)))
    gemm_mfma<256, 128><<<(N + 63) / 64, 256, 0, stream>>>(x, wT1_hi, wT1_lo, dinv, buffA, N);
    gather_nodes<128, true><<<(N + 3) / 4, 256, 0, stream>>>(buffA, csr, rowptr, dinv, b1, buffB, N);

    // layer 2: buffA = dinv ⊙ (buffB @ W2); out = gather(buffA) + b2
    gemm_mfma<128, 64><<<(N + 63) / 64, 256, 0, stream>>>(buffB, wT2_hi, wT2_lo, dinv, buffA, N);
    gather_nodes<64, false><<<(N + 3) / 4, 256, 0, stream>>>(buffA, csr, rowptr, dinv, b2, out, N);
}

// Round 6
// 442.636 us; speedup vs baseline: 1.7851x; 1.0139x over previous
//
#include <hip/hip_runtime.h>

// ---------------------------------------------------------------------------
// GCN 2-layer forward, CSR-gather formulation:
//   hs = dinv ⊙ (X @ W)   (GEMM epilogue scale, stored bf16)
//   out[i] = dinv[i]*(hs[i] + Σ_{j∈in(i)} hs[j]) + b
// GEMM1: split-bf16 MFMA (x fp32 -> hi/lo, 3 MFMA). GEMM2: bf16 A, split W (2 MFMA).
// Intermediates (hs1, h2, gs2) stored bf16 -> gather traffic halved.
// Dropout mask = JAX threefry2x32, key(42), partitionable fold (o0^o1), p=0.5.
//   (verified rounds 3-5)
// ---------------------------------------------------------------------------

typedef __attribute__((ext_vector_type(8))) short bf16x8;          // MFMA A/B
typedef __attribute__((ext_vector_type(4))) float f32x4;           // MFMA C/D
typedef __attribute__((ext_vector_type(8))) unsigned short us8;

__device__ __forceinline__ unsigned tf_rotl(unsigned x, int d) {
    return (x << d) | (x >> (32 - d));
}

__device__ __forceinline__ bool dropout_keep(unsigned flat_idx) {
    const unsigned K0 = 0u, K1 = 42u;
    const unsigned K2 = K0 ^ K1 ^ 0x1BD11BDAu;
    unsigned x0 = 0u, x1 = flat_idx;
    x0 += K0; x1 += K1;
#define TF_R(r) { x0 += x1; x1 = tf_rotl(x1, (r)); x1 ^= x0; }
    TF_R(13) TF_R(15) TF_R(26) TF_R(6)
    x0 += K1; x1 += K2 + 1u;
    TF_R(17) TF_R(29) TF_R(16) TF_R(24)
    x0 += K2; x1 += K0 + 2u;
    TF_R(13) TF_R(15) TF_R(26) TF_R(6)
    x0 += K0; x1 += K1 + 3u;
    TF_R(17) TF_R(29) TF_R(16) TF_R(24)
    x0 += K1; x1 += K2 + 4u;
    TF_R(13) TF_R(15) TF_R(26) TF_R(6)
    x0 += K2; x1 += K0 + 5u;
#undef TF_R
    return (((x0 ^ x1) >> 31) & 1u) == 0u;   // fold bits1^bits2, keep if < 2^31
}

// ---- bf16 helpers ----------------------------------------------------------
__device__ __forceinline__ unsigned short bf16_rn(float x) {
    unsigned u = __float_as_uint(x);
    unsigned r = u + 0x7FFFu + ((u >> 16) & 1u);
    return (unsigned short)(r >> 16);
}
__device__ __forceinline__ void split_bf16(float x, unsigned short& h, unsigned short& l) {
    h = bf16_rn(x);
    float fh = __uint_as_float(((unsigned)h) << 16);
    l = bf16_rn(x - fh);
}
__device__ __forceinline__ void split4(float4 v, ushort4& h, ushort4& l) {
    unsigned short h0, h1, h2, h3, l0, l1, l2, l3;
    split_bf16(v.x, h0, l0); split_bf16(v.y, h1, l1);
    split_bf16(v.z, h2, l2); split_bf16(v.w, h3, l3);
    h = make_ushort4(h0, h1, h2, h3);
    l = make_ushort4(l0, l1, l2, l3);
}

// int32 vs int64 edge-index autodetect (values < 50000 -> i64 hi words are 0).
// All loads hit the same cache line; wave-uniform -> scalarized.
__device__ __forceinline__ int ei_stride(const int* __restrict__ ei) {
    bool i64 = true;
#pragma unroll
    for (int k = 1; k <= 15; k += 2) i64 = i64 && (ei[k] == 0);
    return i64 ? 2 : 1;
}

__global__ void count_deg(const int* __restrict__ ei, unsigned* __restrict__ deg, int E) {
    int e = blockIdx.x * blockDim.x + threadIdx.x;
    if (e >= E) return;
    size_t st = ei_stride(ei);
    atomicAdd(&deg[ei[((size_t)E + e) * st]], 1u);
}

__global__ void make_dinv(const unsigned* __restrict__ deg, float* __restrict__ dinv, int N) {
    int i = blockIdx.x * blockDim.x + threadIdx.x;
    if (i < N) dinv[i] = rsqrtf((float)(deg[i] + 1u));  // +1 = self loop
}

// single-block exclusive scan: rowptr[0..N] from deg[0..N-1]
__global__ __launch_bounds__(1024)
void scan_deg(const unsigned* __restrict__ deg, unsigned* __restrict__ rowptr, int N) {
    __shared__ unsigned part[1024];
    const int t = threadIdx.x;
    const int chunk = (N + 1023) / 1024;
    const int lo = t * chunk;
    const int hi = min(lo + chunk, N);
    unsigned s = 0;
    for (int i = lo; i < hi; ++i) s += deg[i];
    part[t] = s;
    __syncthreads();
    for (int off = 1; off < 1024; off <<= 1) {
        unsigned v = (t >= off) ? part[t - off] : 0u;
        __syncthreads();
        part[t] += v;
        __syncthreads();
    }
    unsigned run = (t == 0) ? 0u : part[t - 1];
    for (int i = lo; i < hi; ++i) { rowptr[i] = run; run += deg[i]; }
    if (lo < N && hi == N) rowptr[N] = run;
}

__global__ void fill_csr(const int* __restrict__ ei, const unsigned* __restrict__ rowptr,
                         unsigned* __restrict__ cursor, int* __restrict__ csr, int E) {
    int e = blockIdx.x * blockDim.x + threadIdx.x;
    if (e >= E) return;
    size_t st = ei_stride(ei);
    int s = ei[(size_t)e * st];
    int d = ei[((size_t)E + e) * st];
    unsigned pos = atomicAdd(&cursor[d], 1u);
    csr[rowptr[d] + pos] = s;
}

// Prep: wT_hi/lo[n*K + k] = split_bf16(W[k*NOUT + n])   (one-time, tiny)
__global__ void split_wT(const float* __restrict__ W, unsigned short* __restrict__ wT_hi,
                         unsigned short* __restrict__ wT_lo, int K, int NOUT) {
    int idx = blockIdx.x * blockDim.x + threadIdx.x;
    if (idx >= K * NOUT) return;
    int k = idx / NOUT, n = idx % NOUT;
    unsigned short h, l;
    split_bf16(W[idx], h, l);
    wT_hi[(size_t)n * K + k] = h;
    wT_lo[(size_t)n * K + k] = l;
}

// ---------------------------------------------------------------------------
// Yb[r, NOUT_] = bf16( scale[r] * (X[r,:] @ W) ), MFMA 16x16x32.
// SPLITA: X fp32, split hi/lo (3 MFMA/tile). !SPLITA: X bf16 (2 MFMA/tile).
// Block: 256 threads (4 waves), BM=64, BK=32; wave owns 4 row-tiles x CT col-tiles.
// D layout: row=(l>>4)*4+j, col=l&15 (m89-verified).
// ---------------------------------------------------------------------------
template <int K_, int NOUT_, bool SPLITA>
__global__ __launch_bounds__(256)
void gemm_mfma(const void* __restrict__ Xv, const unsigned short* __restrict__ wT_hi,
               const unsigned short* __restrict__ wT_lo, const float* __restrict__ scale,
               unsigned short* __restrict__ Yb, int nrows) {
    constexpr int BM = 64, BK = 32, NKT = K_ / BK;
    constexpr int CT = NOUT_ / 64;            // col-tiles per wave
    constexpr int LDW = BK + 8;               // 80B row stride (16B multiple)
    constexpr int WPT = NOUT_ / 32;           // ushort4/thread/half for W staging

    __shared__ __attribute__((aligned(16))) unsigned short xs_hi[BM][LDW];
    __shared__ __attribute__((aligned(16))) unsigned short xs_lo[SPLITA ? BM : 1][SPLITA ? LDW : 1];
    __shared__ __attribute__((aligned(16))) unsigned short ws_hi[NOUT_][LDW];
    __shared__ __attribute__((aligned(16))) unsigned short ws_lo[NOUT_][LDW];

    const int t = threadIdx.x;
    const int wave = t >> 6, lane = t & 63;
    const int m16 = lane & 15, kg = lane >> 4;
    const int row0 = blockIdx.x * BM;
    const int n0 = wave * (16 * CT);

    const float* Xf = (const float*)Xv;
    const unsigned short* Xb = (const unsigned short*)Xv;

    f32x4 acc[4][CT];
#pragma unroll
    for (int r = 0; r < 4; ++r)
#pragma unroll
        for (int c = 0; c < CT; ++c) acc[r][c] = {0.f, 0.f, 0.f, 0.f};

    float4 xpre[2];
    us8 xpre_b;
    ushort4 wpre_h[WPT], wpre_l[WPT];

    // prefetch K-step 0
    if constexpr (SPLITA) {
#pragma unroll
        for (int i = 0; i < 2; ++i) {
            int idx = t + i * 256;
            int r = idx >> 3, c4 = idx & 7;
            int gr = row0 + r;
            xpre[i] = (gr < nrows) ? *(const float4*)&Xf[(size_t)gr * K_ + c4 * 4]
                                   : make_float4(0.f, 0.f, 0.f, 0.f);
        }
    } else {
        int r = t >> 2, c8 = t & 3;
        int gr = row0 + r;
        xpre_b = (gr < nrows) ? *(const us8*)&Xb[(size_t)gr * K_ + c8 * 8] : (us8)0;
    }
#pragma unroll
    for (int i = 0; i < WPT; ++i) {
        int idx = t + i * 256;
        int n = idx >> 3, c4 = idx & 7;
        wpre_h[i] = *(const ushort4*)&wT_hi[(size_t)n * K_ + c4 * 4];
        wpre_l[i] = *(const ushort4*)&wT_lo[(size_t)n * K_ + c4 * 4];
    }

    for (int kb = 0; kb < NKT; ++kb) {
        // stage prefetched regs -> LDS
        if constexpr (SPLITA) {
#pragma unroll
            for (int i = 0; i < 2; ++i) {
                int idx = t + i * 256;
                int r = idx >> 3, c4 = idx & 7;
                ushort4 h, l;
                split4(xpre[i], h, l);
                *(ushort4*)&xs_hi[r][c4 * 4] = h;
                *(ushort4*)&xs_lo[r][c4 * 4] = l;
            }
        } else {
            int r = t >> 2, c8 = t & 3;
            *(us8*)&xs_hi[r][c8 * 8] = xpre_b;
        }
#pragma unroll
        for (int i = 0; i < WPT; ++i) {
            int idx = t + i * 256;
            int n = idx >> 3, c4 = idx & 7;
            *(ushort4*)&ws_hi[n][c4 * 4] = wpre_h[i];
            *(ushort4*)&ws_lo[n][c4 * 4] = wpre_l[i];
        }
        __syncthreads();

        // issue next K-step's global loads (hide HBM under MFMA)
        if (kb + 1 < NKT) {
            const int koff = (kb + 1) * BK;
            if constexpr (SPLITA) {
#pragma unroll
                for (int i = 0; i < 2; ++i) {
                    int idx = t + i * 256;
                    int r = idx >> 3, c4 = idx & 7;
                    int gr = row0 + r;
                    xpre[i] = (gr < nrows) ? *(const float4*)&Xf[(size_t)gr * K_ + koff + c4 * 4]
                                           : make_float4(0.f, 0.f, 0.f, 0.f);
                }
            } else {
                int r = t >> 2, c8 = t & 3;
                int gr = row0 + r;
                xpre_b = (gr < nrows) ? *(const us8*)&Xb[(size_t)gr * K_ + koff + c8 * 8] : (us8)0;
            }
#pragma unroll
            for (int i = 0; i < WPT; ++i) {
                int idx = t + i * 256;
                int n = idx >> 3, c4 = idx & 7;
                wpre_h[i] = *(const ushort4*)&wT_hi[(size_t)n * K_ + koff + c4 * 4];
                wpre_l[i] = *(const ushort4*)&wT_lo[(size_t)n * K_ + koff + c4 * 4];
            }
        }

        // compute on LDS tiles
        bf16x8 bh[CT], bl[CT];
#pragma unroll
        for (int c = 0; c < CT; ++c) {
            bh[c] = *(const bf16x8*)&ws_hi[n0 + c * 16 + m16][kg * 8];
            bl[c] = *(const bf16x8*)&ws_lo[n0 + c * 16 + m16][kg * 8];
        }
#pragma unroll
        for (int r = 0; r < 4; ++r) {
            bf16x8 ah = *(const bf16x8*)&xs_hi[r * 16 + m16][kg * 8];
            if constexpr (SPLITA) {
                bf16x8 al = *(const bf16x8*)&xs_lo[r * 16 + m16][kg * 8];
#pragma unroll
                for (int c = 0; c < CT; ++c) {
                    acc[r][c] = __builtin_amdgcn_mfma_f32_16x16x32_bf16(ah, bh[c], acc[r][c], 0, 0, 0);
                    acc[r][c] = __builtin_amdgcn_mfma_f32_16x16x32_bf16(ah, bl[c], acc[r][c], 0, 0, 0);
                    acc[r][c] = __builtin_amdgcn_mfma_f32_16x16x32_bf16(al, bh[c], acc[r][c], 0, 0, 0);
                }
            } else {
#pragma unroll
                for (int c = 0; c < CT; ++c) {
                    acc[r][c] = __builtin_amdgcn_mfma_f32_16x16x32_bf16(ah, bh[c], acc[r][c], 0, 0, 0);
                    acc[r][c] = __builtin_amdgcn_mfma_f32_16x16x32_bf16(ah, bl[c], acc[r][c], 0, 0, 0);
                }
            }
        }
        __syncthreads();
    }

    // epilogue: scale rows by dinv, convert to bf16, store
#pragma unroll
    for (int r = 0; r < 4; ++r) {
#pragma unroll
        for (int j = 0; j < 4; ++j) {
            int gr = row0 + r * 16 + kg * 4 + j;
            if (gr < nrows) {
                float s = scale[gr];
#pragma unroll
                for (int c = 0; c < CT; ++c)
                    Yb[(size_t)gr * NOUT_ + n0 + c * 16 + m16] = bf16_rn(acc[r][c][j] * s);
            }
        }
    }
}

// ---------------------------------------------------------------------------
// Gather layer 1 (F=128, bf16 in, bf16 out, relu+dropout fused).
// One wave per node; lane owns features 2*lane, 2*lane+1 (one uint).
// ---------------------------------------------------------------------------
__global__ __launch_bounds__(256)
void gather_drop(const unsigned* __restrict__ hs /*bf16x2*/, const int* __restrict__ csr,
                 const unsigned* __restrict__ rowptr, const float* __restrict__ dinv,
                 const float* __restrict__ bias, unsigned* __restrict__ outb /*bf16x2*/,
                 int N) {
    const int node = blockIdx.x * 4 + (threadIdx.x >> 6);
    if (node >= N) return;
    const int lane = threadIdx.x & 63;
    const unsigned beg = rowptr[node];
    const unsigned end = rowptr[node + 1];
    const float dn = dinv[node];

    unsigned v = hs[(size_t)node * 64 + lane];
    float ax = __uint_as_float(v << 16);
    float ay = __uint_as_float(v & 0xffff0000u);
    for (unsigned k = beg; k < end; ++k) {
        int j = csr[k];
        unsigned w = hs[(size_t)j * 64 + lane];
        ax += __uint_as_float(w << 16);
        ay += __uint_as_float(w & 0xffff0000u);
    }
    const int f0 = 2 * lane;
    float o0 = fmaxf(dn * ax + bias[f0], 0.0f);
    float o1 = fmaxf(dn * ay + bias[f0 + 1], 0.0f);
    unsigned base = (unsigned)node * 128u + (unsigned)f0;
    o0 = dropout_keep(base) ? 2.0f * o0 : 0.0f;
    o1 = dropout_keep(base + 1u) ? 2.0f * o1 : 0.0f;
    outb[(size_t)node * 64 + lane] =
        (unsigned)bf16_rn(o0) | ((unsigned)bf16_rn(o1) << 16);
}

// ---------------------------------------------------------------------------
// Gather layer 2 (F=64, bf16 in, f32 out). One wave per node, lane = feature.
// ---------------------------------------------------------------------------
__global__ __launch_bounds__(256)
void gather_out(const unsigned short* __restrict__ hs /*bf16*/, const int* __restrict__ csr,
                const unsigned* __restrict__ rowptr, const float* __restrict__ dinv,
                const float* __restrict__ bias, float* __restrict__ outp, int N) {
    const int node = blockIdx.x * 4 + (threadIdx.x >> 6);
    if (node >= N) return;
    const int lane = threadIdx.x & 63;
    const unsigned beg = rowptr[node];
    const unsigned end = rowptr[node + 1];
    const float dn = dinv[node];

    float acc = __uint_as_float(((unsigned)hs[(size_t)node * 64 + lane]) << 16);
    for (unsigned k = beg; k < end; ++k) {
        int j = csr[k];
        acc += __uint_as_float(((unsigned)hs[(size_t)j * 64 + lane]) << 16);
    }
    outp[(size_t)node * 64 + lane] = dn * acc + bias[lane];
}

extern "C" void kernel_launch(void* const* d_in, const int* in_sizes, int n_in,
                              void* d_out, int out_size, void* d_ws, size_t ws_size,
                              hipStream_t stream) {
    const float* x  = (const float*)d_in[0];
    const int*   ei = (const int*)d_in[1];
    const float* W1 = (const float*)d_in[2];
    const float* b1 = (const float*)d_in[3];
    const float* W2 = (const float*)d_in[4];
    const float* b2 = (const float*)d_in[5];
    float* out = (float*)d_out;

    const int Fdim = 256, Hdim = 128, Cdim = 64;
    const int N = in_sizes[0] / Fdim;   // 50000
    const int E = in_sizes[1] / 2;      // 800000

    // workspace: wT1_hi|lo (256*128 us ea) | wT2_hi|lo (128*64 us ea) |
    //   buffA[N*128] bf16 (hs1, then gs2) | buffB[N*128] bf16 (h2) |
    //   deg[N] | cursor[N] | dinv[N] | rowptr[N+1] | csr[E]
    unsigned short* wT1_hi = (unsigned short*)d_ws;
    unsigned short* wT1_lo = wT1_hi + 256 * 128;
    unsigned short* wT2_hi = wT1_lo + 256 * 128;
    unsigned short* wT2_lo = wT2_hi + 128 * 64;
    unsigned short* buffA  = wT2_lo + 128 * 64;          // byte off 163840, 16B-aligned
    unsigned short* buffB  = buffA + (size_t)N * Hdim;
    unsigned* deg    = (unsigned*)(buffB + (size_t)N * Hdim);
    unsigned* cursor = deg + N;
    float*    dinv   = (float*)(cursor + N);
    unsigned* rowptr = (unsigned*)(dinv + N);
    int*      csr    = (int*)(rowptr + (N + 1));

    hipMemsetAsync(deg, 0, 2 * (size_t)N * sizeof(unsigned), stream);

    count_deg<<<(E + 255) / 256, 256, 0, stream>>>(ei, deg, E);
    make_dinv<<<(N + 255) / 256, 256, 0, stream>>>(deg, dinv, N);
    scan_deg<<<1, 1024, 0, stream>>>(deg, rowptr, N);
    fill_csr<<<(E + 255) / 256, 256, 0, stream>>>(ei, rowptr, cursor, csr, E);

    split_wT<<<(256 * 128 + 255) / 256, 256, 0, stream>>>(W1, wT1_hi, wT1_lo, 256, 128);
    split_wT<<<(128 * 64 + 255) / 256, 256, 0, stream>>>(W2, wT2_hi, wT2_lo, 128, 64);

    // layer 1: buffA = bf16(dinv ⊙ (x @ W1)); buffB = bf16(drop(relu(gather(buffA))))
    gemm_mfma<256, 128, true><<<(N + 63) / 64, 256, 0, stream>>>(x, wT1_hi, wT1_lo, dinv, buffA, N);
    gather_drop<<<(N + 3) / 4, 256, 0, stream>>>((const unsigned*)buffA, csr, rowptr, dinv, b1,
                                                 (unsigned*)buffB, N);

    // layer 2: buffA = bf16(dinv ⊙ (buffB @ W2)); out = gather(buffA) + b2
    gemm_mfma<128, 64, false><<<(N + 63) / 64, 256, 0, stream>>>(buffB, wT2_hi, wT2_lo, dinv, buffA, N);
    gather_out<<<(N + 3) / 4, 256, 0, stream>>>(buffA, csr, rowptr, dinv, b2, out, N);
}

// Round 7
// 399.717 us; speedup vs baseline: 1.9767x; 1.1074x over previous
//
#include <hip/hip_runtime.h>

// ---------------------------------------------------------------------------
// GCN 2-layer forward, CSR-gather formulation:
//   hs = dinv ⊙ (X @ W)   (GEMM epilogue scale, stored bf16)
//   out[i] = dinv[i]*(hs[i] + Σ_{j∈in(i)} hs[j]) + b
// GEMM1: split-bf16 MFMA (3 MFMA). GEMM2: bf16 A, split W (2 MFMA).
// CSR slots padded to multiples of 8 with a zero-node (row N) -> branch-free
// 8-deep gather batches (8 outstanding loads per wave, latency-bound fix).
// Dropout mask = JAX threefry2x32, key(42), partitionable fold (o0^o1), p=0.5.
//   (verified rounds 3-6)
// ---------------------------------------------------------------------------

typedef __attribute__((ext_vector_type(8))) short bf16x8;          // MFMA A/B
typedef __attribute__((ext_vector_type(4))) float f32x4;           // MFMA C/D
typedef __attribute__((ext_vector_type(8))) unsigned short us8;

__device__ __forceinline__ unsigned tf_rotl(unsigned x, int d) {
    return (x << d) | (x >> (32 - d));
}

__device__ __forceinline__ bool dropout_keep(unsigned flat_idx) {
    const unsigned K0 = 0u, K1 = 42u;
    const unsigned K2 = K0 ^ K1 ^ 0x1BD11BDAu;
    unsigned x0 = 0u, x1 = flat_idx;
    x0 += K0; x1 += K1;
#define TF_R(r) { x0 += x1; x1 = tf_rotl(x1, (r)); x1 ^= x0; }
    TF_R(13) TF_R(15) TF_R(26) TF_R(6)
    x0 += K1; x1 += K2 + 1u;
    TF_R(17) TF_R(29) TF_R(16) TF_R(24)
    x0 += K2; x1 += K0 + 2u;
    TF_R(13) TF_R(15) TF_R(26) TF_R(6)
    x0 += K0; x1 += K1 + 3u;
    TF_R(17) TF_R(29) TF_R(16) TF_R(24)
    x0 += K1; x1 += K2 + 4u;
    TF_R(13) TF_R(15) TF_R(26) TF_R(6)
    x0 += K2; x1 += K0 + 5u;
#undef TF_R
    return (((x0 ^ x1) >> 31) & 1u) == 0u;   // fold bits1^bits2, keep if < 2^31
}

// ---- bf16 helpers ----------------------------------------------------------
__device__ __forceinline__ unsigned short bf16_rn(float x) {
    unsigned u = __float_as_uint(x);
    unsigned r = u + 0x7FFFu + ((u >> 16) & 1u);
    return (unsigned short)(r >> 16);
}
__device__ __forceinline__ void split_bf16(float x, unsigned short& h, unsigned short& l) {
    h = bf16_rn(x);
    float fh = __uint_as_float(((unsigned)h) << 16);
    l = bf16_rn(x - fh);
}
__device__ __forceinline__ void split4(float4 v, ushort4& h, ushort4& l) {
    unsigned short h0, h1, h2, h3, l0, l1, l2, l3;
    split_bf16(v.x, h0, l0); split_bf16(v.y, h1, l1);
    split_bf16(v.z, h2, l2); split_bf16(v.w, h3, l3);
    h = make_ushort4(h0, h1, h2, h3);
    l = make_ushort4(l0, l1, l2, l3);
}

// int32 vs int64 edge-index autodetect (values < 50000 -> i64 hi words are 0).
__device__ __forceinline__ int ei_stride(const int* __restrict__ ei) {
    bool i64 = true;
#pragma unroll
    for (int k = 1; k <= 15; k += 2) i64 = i64 && (ei[k] == 0);
    return i64 ? 2 : 1;
}

__global__ void count_deg(const int* __restrict__ ei, unsigned* __restrict__ deg, int E) {
    int e = blockIdx.x * blockDim.x + threadIdx.x;
    if (e >= E) return;
    size_t st = ei_stride(ei);
    atomicAdd(&deg[ei[((size_t)E + e) * st]], 1u);
}

// exclusive scan over PADDED slot counts (roundup8(deg)); also emits dinv.
__global__ __launch_bounds__(1024)
void scan_deg(const unsigned* __restrict__ deg, unsigned* __restrict__ rowptr,
              float* __restrict__ dinv, int N) {
    __shared__ unsigned part[1024];
    const int t = threadIdx.x;
    const int chunk = (N + 1023) / 1024;
    const int lo = t * chunk;
    const int hi = min(lo + chunk, N);
    unsigned s = 0;
    for (int i = lo; i < hi; ++i) {
        s += (deg[i] + 7u) & ~7u;
        dinv[i] = rsqrtf((float)(deg[i] + 1u));   // +1 = self loop
    }
    part[t] = s;
    __syncthreads();
    for (int off = 1; off < 1024; off <<= 1) {
        unsigned v = (t >= off) ? part[t - off] : 0u;
        __syncthreads();
        part[t] += v;
        __syncthreads();
    }
    unsigned run = (t == 0) ? 0u : part[t - 1];
    for (int i = lo; i < hi; ++i) { rowptr[i] = run; run += (deg[i] + 7u) & ~7u; }
    if (lo < N && hi == N) rowptr[N] = run;
}

// prefill csr with the zero-node index N (pad slots resolve to an all-zero row)
__global__ void fill_pad(int* __restrict__ csr, int total, int N) {
    int i = blockIdx.x * blockDim.x + threadIdx.x;
    if (i < total) csr[i] = N;
}

__global__ void fill_csr(const int* __restrict__ ei, const unsigned* __restrict__ rowptr,
                         unsigned* __restrict__ cursor, int* __restrict__ csr, int E) {
    int e = blockIdx.x * blockDim.x + threadIdx.x;
    if (e >= E) return;
    size_t st = ei_stride(ei);
    int s = ei[(size_t)e * st];
    int d = ei[((size_t)E + e) * st];
    unsigned pos = atomicAdd(&cursor[d], 1u);
    csr[rowptr[d] + pos] = s;
}

// Prep: wT_hi/lo[n*K + k] = split_bf16(W[k*NOUT + n])   (one-time, tiny)
__global__ void split_wT(const float* __restrict__ W, unsigned short* __restrict__ wT_hi,
                         unsigned short* __restrict__ wT_lo, int K, int NOUT) {
    int idx = blockIdx.x * blockDim.x + threadIdx.x;
    if (idx >= K * NOUT) return;
    int k = idx / NOUT, n = idx % NOUT;
    unsigned short h, l;
    split_bf16(W[idx], h, l);
    wT_hi[(size_t)n * K + k] = h;
    wT_lo[(size_t)n * K + k] = l;
}

// ---------------------------------------------------------------------------
// Yb[r, NOUT_] = bf16( scale[r] * (X[r,:] @ W) ), MFMA 16x16x32.
// Also zeroes the zero-node row (row nrows) from block 0.
// ---------------------------------------------------------------------------
template <int K_, int NOUT_, bool SPLITA>
__global__ __launch_bounds__(256)
void gemm_mfma(const void* __restrict__ Xv, const unsigned short* __restrict__ wT_hi,
               const unsigned short* __restrict__ wT_lo, const float* __restrict__ scale,
               unsigned short* __restrict__ Yb, int nrows) {
    constexpr int BM = 64, BK = 32, NKT = K_ / BK;
    constexpr int CT = NOUT_ / 64;            // col-tiles per wave
    constexpr int LDW = BK + 8;               // 80B row stride (16B multiple)
    constexpr int WPT = NOUT_ / 32;           // ushort4/thread/half for W staging

    __shared__ __attribute__((aligned(16))) unsigned short xs_hi[BM][LDW];
    __shared__ __attribute__((aligned(16))) unsigned short xs_lo[SPLITA ? BM : 1][SPLITA ? LDW : 1];
    __shared__ __attribute__((aligned(16))) unsigned short ws_hi[NOUT_][LDW];
    __shared__ __attribute__((aligned(16))) unsigned short ws_lo[NOUT_][LDW];

    const int t = threadIdx.x;
    const int wave = t >> 6, lane = t & 63;
    const int m16 = lane & 15, kg = lane >> 4;
    const int row0 = blockIdx.x * BM;
    const int n0 = wave * (16 * CT);

    // zero-node row for padded gathers
    if (blockIdx.x == 0 && t < NOUT_ / 8) {
        us8 z = (us8)0;
        *(us8*)&Yb[(size_t)nrows * NOUT_ + t * 8] = z;
    }

    const float* Xf = (const float*)Xv;
    const unsigned short* Xb = (const unsigned short*)Xv;

    f32x4 acc[4][CT];
#pragma unroll
    for (int r = 0; r < 4; ++r)
#pragma unroll
        for (int c = 0; c < CT; ++c) acc[r][c] = {0.f, 0.f, 0.f, 0.f};

    float4 xpre[2];
    us8 xpre_b;
    ushort4 wpre_h[WPT], wpre_l[WPT];

    if constexpr (SPLITA) {
#pragma unroll
        for (int i = 0; i < 2; ++i) {
            int idx = t + i * 256;
            int r = idx >> 3, c4 = idx & 7;
            int gr = row0 + r;
            xpre[i] = (gr < nrows) ? *(const float4*)&Xf[(size_t)gr * K_ + c4 * 4]
                                   : make_float4(0.f, 0.f, 0.f, 0.f);
        }
    } else {
        int r = t >> 2, c8 = t & 3;
        int gr = row0 + r;
        xpre_b = (gr < nrows) ? *(const us8*)&Xb[(size_t)gr * K_ + c8 * 8] : (us8)0;
    }
#pragma unroll
    for (int i = 0; i < WPT; ++i) {
        int idx = t + i * 256;
        int n = idx >> 3, c4 = idx & 7;
        wpre_h[i] = *(const ushort4*)&wT_hi[(size_t)n * K_ + c4 * 4];
        wpre_l[i] = *(const ushort4*)&wT_lo[(size_t)n * K_ + c4 * 4];
    }

    for (int kb = 0; kb < NKT; ++kb) {
        if constexpr (SPLITA) {
#pragma unroll
            for (int i = 0; i < 2; ++i) {
                int idx = t + i * 256;
                int r = idx >> 3, c4 = idx & 7;
                ushort4 h, l;
                split4(xpre[i], h, l);
                *(ushort4*)&xs_hi[r][c4 * 4] = h;
                *(ushort4*)&xs_lo[r][c4 * 4] = l;
            }
        } else {
            int r = t >> 2, c8 = t & 3;
            *(us8*)&xs_hi[r][c8 * 8] = xpre_b;
        }
#pragma unroll
        for (int i = 0; i < WPT; ++i) {
            int idx = t + i * 256;
            int n = idx >> 3, c4 = idx & 7;
            *(ushort4*)&ws_hi[n][c4 * 4] = wpre_h[i];
            *(ushort4*)&ws_lo[n][c4 * 4] = wpre_l[i];
        }
        __syncthreads();

        if (kb + 1 < NKT) {
            const int koff = (kb + 1) * BK;
            if constexpr (SPLITA) {
#pragma unroll
                for (int i = 0; i < 2; ++i) {
                    int idx = t + i * 256;
                    int r = idx >> 3, c4 = idx & 7;
                    int gr = row0 + r;
                    xpre[i] = (gr < nrows) ? *(const float4*)&Xf[(size_t)gr * K_ + koff + c4 * 4]
                                           : make_float4(0.f, 0.f, 0.f, 0.f);
                }
            } else {
                int r = t >> 2, c8 = t & 3;
                int gr = row0 + r;
                xpre_b = (gr < nrows) ? *(const us8*)&Xb[(size_t)gr * K_ + koff + c8 * 8] : (us8)0;
            }
#pragma unroll
            for (int i = 0; i < WPT; ++i) {
                int idx = t + i * 256;
                int n = idx >> 3, c4 = idx & 7;
                wpre_h[i] = *(const ushort4*)&wT_hi[(size_t)n * K_ + koff + c4 * 4];
                wpre_l[i] = *(const ushort4*)&wT_lo[(size_t)n * K_ + koff + c4 * 4];
            }
        }

        bf16x8 bh[CT], bl[CT];
#pragma unroll
        for (int c = 0; c < CT; ++c) {
            bh[c] = *(const bf16x8*)&ws_hi[n0 + c * 16 + m16][kg * 8];
            bl[c] = *(const bf16x8*)&ws_lo[n0 + c * 16 + m16][kg * 8];
        }
#pragma unroll
        for (int r = 0; r < 4; ++r) {
            bf16x8 ah = *(const bf16x8*)&xs_hi[r * 16 + m16][kg * 8];
            if constexpr (SPLITA) {
                bf16x8 al = *(const bf16x8*)&xs_lo[r * 16 + m16][kg * 8];
#pragma unroll
                for (int c = 0; c < CT; ++c) {
                    acc[r][c] = __builtin_amdgcn_mfma_f32_16x16x32_bf16(ah, bh[c], acc[r][c], 0, 0, 0);
                    acc[r][c] = __builtin_amdgcn_mfma_f32_16x16x32_bf16(ah, bl[c], acc[r][c], 0, 0, 0);
                    acc[r][c] = __builtin_amdgcn_mfma_f32_16x16x32_bf16(al, bh[c], acc[r][c], 0, 0, 0);
                }
            } else {
#pragma unroll
                for (int c = 0; c < CT; ++c) {
                    acc[r][c] = __builtin_amdgcn_mfma_f32_16x16x32_bf16(ah, bh[c], acc[r][c], 0, 0, 0);
                    acc[r][c] = __builtin_amdgcn_mfma_f32_16x16x32_bf16(ah, bl[c], acc[r][c], 0, 0, 0);
                }
            }
        }
        __syncthreads();
    }

#pragma unroll
    for (int r = 0; r < 4; ++r) {
#pragma unroll
        for (int j = 0; j < 4; ++j) {
            int gr = row0 + r * 16 + kg * 4 + j;
            if (gr < nrows) {
                float s = scale[gr];
#pragma unroll
                for (int c = 0; c < CT; ++c)
                    Yb[(size_t)gr * NOUT_ + n0 + c * 16 + m16] = bf16_rn(acc[r][c][j] * s);
            }
        }
    }
}

// ---------------------------------------------------------------------------
// Gather layer 1 (F=128, bf16 in/out, relu+dropout fused). 8-deep batches.
// ---------------------------------------------------------------------------
__global__ __launch_bounds__(256)
void gather_drop(const unsigned* __restrict__ hs /*bf16x2*/, const int* __restrict__ csr,
                 const unsigned* __restrict__ rowptr, const float* __restrict__ dinv,
                 const float* __restrict__ bias, unsigned* __restrict__ outb /*bf16x2*/,
                 int N) {
    const int node = blockIdx.x * 4 + (threadIdx.x >> 6);
    if (node >= N) return;
    const int lane = threadIdx.x & 63;
    const unsigned beg = rowptr[node];
    const unsigned end = rowptr[node + 1];   // (end-beg) % 8 == 0, pads -> row N (zeros)
    const float dn = dinv[node];

    unsigned v = hs[(size_t)node * 64 + lane];
    float ax = __uint_as_float(v << 16);
    float ay = __uint_as_float(v & 0xffff0000u);
    for (unsigned k = beg; k < end; k += 8) {
        int j[8];
#pragma unroll
        for (int u = 0; u < 8; ++u) j[u] = csr[k + u];
        unsigned w[8];
#pragma unroll
        for (int u = 0; u < 8; ++u) w[u] = hs[(size_t)j[u] * 64 + lane];
#pragma unroll
        for (int u = 0; u < 8; ++u) {
            ax += __uint_as_float(w[u] << 16);
            ay += __uint_as_float(w[u] & 0xffff0000u);
        }
    }
    const int f0 = 2 * lane;
    float o0 = fmaxf(dn * ax + bias[f0], 0.0f);
    float o1 = fmaxf(dn * ay + bias[f0 + 1], 0.0f);
    unsigned base = (unsigned)node * 128u + (unsigned)f0;
    o0 = dropout_keep(base) ? 2.0f * o0 : 0.0f;
    o1 = dropout_keep(base + 1u) ? 2.0f * o1 : 0.0f;
    outb[(size_t)node * 64 + lane] =
        (unsigned)bf16_rn(o0) | ((unsigned)bf16_rn(o1) << 16);
}

// ---------------------------------------------------------------------------
// Gather layer 2 (F=64, bf16 in, f32 out). 8-deep batches.
// ---------------------------------------------------------------------------
__global__ __launch_bounds__(256)
void gather_out(const unsigned short* __restrict__ hs /*bf16*/, const int* __restrict__ csr,
                const unsigned* __restrict__ rowptr, const float* __restrict__ dinv,
                const float* __restrict__ bias, float* __restrict__ outp, int N) {
    const int node = blockIdx.x * 4 + (threadIdx.x >> 6);
    if (node >= N) return;
    const int lane = threadIdx.x & 63;
    const unsigned beg = rowptr[node];
    const unsigned end = rowptr[node + 1];
    const float dn = dinv[node];

    float acc = __uint_as_float(((unsigned)hs[(size_t)node * 64 + lane]) << 16);
    for (unsigned k = beg; k < end; k += 8) {
        int j[8];
#pragma unroll
        for (int u = 0; u < 8; ++u) j[u] = csr[k + u];
        unsigned short w[8];
#pragma unroll
        for (int u = 0; u < 8; ++u) w[u] = hs[(size_t)j[u] * 64 + lane];
#pragma unroll
        for (int u = 0; u < 8; ++u) acc += __uint_as_float(((unsigned)w[u]) << 16);
    }
    outp[(size_t)node * 64 + lane] = dn * acc + bias[lane];
}

extern "C" void kernel_launch(void* const* d_in, const int* in_sizes, int n_in,
                              void* d_out, int out_size, void* d_ws, size_t ws_size,
                              hipStream_t stream) {
    const float* x  = (const float*)d_in[0];
    const int*   ei = (const int*)d_in[1];
    const float* W1 = (const float*)d_in[2];
    const float* b1 = (const float*)d_in[3];
    const float* W2 = (const float*)d_in[4];
    const float* b2 = (const float*)d_in[5];
    float* out = (float*)d_out;

    const int Fdim = 256, Hdim = 128, Cdim = 64;
    const int N = in_sizes[0] / Fdim;   // 50000
    const int E = in_sizes[1] / 2;      // 800000
    const int CSR_CAP = E + 7 * N;      // padded-slot upper bound

    // workspace: wT1_hi|lo (256*128 us ea) | wT2_hi|lo (128*64 us ea) |
    //   buffA[(N+1)*128] bf16 | buffB[N*128] bf16 |
    //   deg[N] | cursor[N] | dinv[N] | rowptr[N+1] | csr[CSR_CAP]
    unsigned short* wT1_hi = (unsigned short*)d_ws;
    unsigned short* wT1_lo = wT1_hi + 256 * 128;
    unsigned short* wT2_hi = wT1_lo + 256 * 128;
    unsigned short* wT2_lo = wT2_hi + 128 * 64;
    unsigned short* buffA  = wT2_lo + 128 * 64;
    unsigned short* buffB  = buffA + (size_t)(N + 1) * Hdim;
    unsigned* deg    = (unsigned*)(buffB + (size_t)N * Hdim);
    unsigned* cursor = deg + N;
    float*    dinv   = (float*)(cursor + N);
    unsigned* rowptr = (unsigned*)(dinv + N);
    int*      csr    = (int*)(rowptr + (N + 1));

    hipMemsetAsync(deg, 0, 2 * (size_t)N * sizeof(unsigned), stream);

    count_deg<<<(E + 255) / 256, 256, 0, stream>>>(ei, deg, E);
    fill_pad<<<(CSR_CAP + 255) / 256, 256, 0, stream>>>(csr, CSR_CAP, N);
    scan_deg<<<1, 1024, 0, stream>>>(deg, rowptr, dinv, N);
    fill_csr<<<(E + 255) / 256, 256, 0, stream>>>(ei, rowptr, cursor, csr, E);

    split_wT<<<(256 * 128 + 255) / 256, 256, 0, stream>>>(W1, wT1_hi, wT1_lo, 256, 128);
    split_wT<<<(128 * 64 + 255) / 256, 256, 0, stream>>>(W2, wT2_hi, wT2_lo, 128, 64);

    // layer 1
    gemm_mfma<256, 128, true><<<(N + 63) / 64, 256, 0, stream>>>(x, wT1_hi, wT1_lo, dinv, buffA, N);
    gather_drop<<<(N + 3) / 4, 256, 0, stream>>>((const unsigned*)buffA, csr, rowptr, dinv, b1,
                                                 (unsigned*)buffB, N);

    // layer 2
    gemm_mfma<128, 64, false><<<(N + 63) / 64, 256, 0, stream>>>(buffB, wT2_hi, wT2_lo, dinv, buffA, N);
    gather_out<<<(N + 3) / 4, 256, 0, stream>>>(buffA, csr, rowptr, dinv, b2, out, N);
}

// Round 8
// 288.170 us; speedup vs baseline: 2.7419x; 1.3871x over previous
//
#include <hip/hip_runtime.h>

// ---------------------------------------------------------------------------
// GCN 2-layer forward, CSR-gather formulation:
//   hs = dinv ⊙ (X @ W)   (GEMM epilogue scale, stored bf16)
//   out[i] = dinv[i]*(hs[i] + Σ_{j∈in(i)} hs[j]) + b
// GEMM1: split-bf16 MFMA (3 MFMA). GEMM2: bf16 A, split W (2 MFMA).
// CSR slots padded to multiples of 8 with a zero-node (row N) -> branch-free
// 8-deep gather batches. Rowptr built with a 3-phase device-wide scan
// (round 7's single-block scan was 132 us at 0.16% occupancy).
// Dropout mask = JAX threefry2x32, key(42), partitionable fold (o0^o1), p=0.5.
//   (verified rounds 3-7)
// ---------------------------------------------------------------------------

typedef __attribute__((ext_vector_type(8))) short bf16x8;          // MFMA A/B
typedef __attribute__((ext_vector_type(4))) float f32x4;           // MFMA C/D
typedef __attribute__((ext_vector_type(8))) unsigned short us8;

__device__ __forceinline__ unsigned tf_rotl(unsigned x, int d) {
    return (x << d) | (x >> (32 - d));
}

__device__ __forceinline__ bool dropout_keep(unsigned flat_idx) {
    const unsigned K0 = 0u, K1 = 42u;
    const unsigned K2 = K0 ^ K1 ^ 0x1BD11BDAu;
    unsigned x0 = 0u, x1 = flat_idx;
    x0 += K0; x1 += K1;
#define TF_R(r) { x0 += x1; x1 = tf_rotl(x1, (r)); x1 ^= x0; }
    TF_R(13) TF_R(15) TF_R(26) TF_R(6)
    x0 += K1; x1 += K2 + 1u;
    TF_R(17) TF_R(29) TF_R(16) TF_R(24)
    x0 += K2; x1 += K0 + 2u;
    TF_R(13) TF_R(15) TF_R(26) TF_R(6)
    x0 += K0; x1 += K1 + 3u;
    TF_R(17) TF_R(29) TF_R(16) TF_R(24)
    x0 += K1; x1 += K2 + 4u;
    TF_R(13) TF_R(15) TF_R(26) TF_R(6)
    x0 += K2; x1 += K0 + 5u;
#undef TF_R
    return (((x0 ^ x1) >> 31) & 1u) == 0u;   // fold bits1^bits2, keep if < 2^31
}

// ---- bf16 helpers ----------------------------------------------------------
__device__ __forceinline__ unsigned short bf16_rn(float x) {
    unsigned u = __float_as_uint(x);
    unsigned r = u + 0x7FFFu + ((u >> 16) & 1u);
    return (unsigned short)(r >> 16);
}
__device__ __forceinline__ void split_bf16(float x, unsigned short& h, unsigned short& l) {
    h = bf16_rn(x);
    float fh = __uint_as_float(((unsigned)h) << 16);
    l = bf16_rn(x - fh);
}
__device__ __forceinline__ void split4(float4 v, ushort4& h, ushort4& l) {
    unsigned short h0, h1, h2, h3, l0, l1, l2, l3;
    split_bf16(v.x, h0, l0); split_bf16(v.y, h1, l1);
    split_bf16(v.z, h2, l2); split_bf16(v.w, h3, l3);
    h = make_ushort4(h0, h1, h2, h3);
    l = make_ushort4(l0, l1, l2, l3);
}

// int32 vs int64 edge-index autodetect (values < 50000 -> i64 hi words are 0).
__device__ __forceinline__ int ei_stride(const int* __restrict__ ei) {
    bool i64 = true;
#pragma unroll
    for (int k = 1; k <= 15; k += 2) i64 = i64 && (ei[k] == 0);
    return i64 ? 2 : 1;
}

__global__ void count_deg(const int* __restrict__ ei, unsigned* __restrict__ deg, int E) {
    int e = blockIdx.x * blockDim.x + threadIdx.x;
    if (e >= E) return;
    size_t st = ei_stride(ei);
    atomicAdd(&deg[ei[((size_t)E + e) * st]], 1u);
}

// ---------------------------------------------------------------------------
// 3-phase device-wide exclusive scan of padded degrees (pad8), fused dinv.
// ---------------------------------------------------------------------------
__global__ __launch_bounds__(256)
void scan_phase1(const unsigned* __restrict__ deg, unsigned* __restrict__ blockSums,
                 float* __restrict__ dinv, int N) {
    const int i = blockIdx.x * 256 + threadIdx.x;
    const int lane = threadIdx.x & 63, wave = threadIdx.x >> 6;
    unsigned v = 0;
    if (i < N) {
        unsigned d = deg[i];
        v = (d + 7u) & ~7u;
        dinv[i] = rsqrtf((float)(d + 1u));   // +1 = self loop
    }
    unsigned s = v;
#pragma unroll
    for (int o = 32; o > 0; o >>= 1) s += __shfl_down(s, o, 64);
    __shared__ unsigned ws[4];
    if (lane == 0) ws[wave] = s;
    __syncthreads();
    if (threadIdx.x == 0)
        blockSums[blockIdx.x] = ws[0] + ws[1] + ws[2] + ws[3];
}

__global__ __launch_bounds__(1024)
void scan_phase2(unsigned* __restrict__ blockSums, int nb) {
    __shared__ unsigned s[1024];
    const int t = threadIdx.x;
    unsigned v = (t < nb) ? blockSums[t] : 0u;
    s[t] = v;
    __syncthreads();
    for (int off = 1; off < 1024; off <<= 1) {
        unsigned u = (t >= off) ? s[t - off] : 0u;
        __syncthreads();
        s[t] += u;
        __syncthreads();
    }
    if (t < nb) blockSums[t] = s[t] - v;   // exclusive
}

__global__ __launch_bounds__(256)
void scan_phase3(const unsigned* __restrict__ deg, const unsigned* __restrict__ blockSums,
                 unsigned* __restrict__ rowptr, int N) {
    const int i = blockIdx.x * 256 + threadIdx.x;
    const int t = threadIdx.x;
    unsigned v = 0;
    if (i < N) v = (deg[i] + 7u) & ~7u;
    __shared__ unsigned s[256];
    s[t] = v;
    __syncthreads();
    for (int off = 1; off < 256; off <<= 1) {
        unsigned u = (t >= off) ? s[t - off] : 0u;
        __syncthreads();
        s[t] += u;
        __syncthreads();
    }
    const unsigned incl = s[t];
    const unsigned off0 = blockSums[blockIdx.x];
    if (i < N) {
        rowptr[i] = off0 + incl - v;
        if (i == N - 1) rowptr[N] = off0 + incl;
    }
}

// prefill csr with the zero-node index N (pad slots resolve to an all-zero row)
__global__ void fill_pad(int* __restrict__ csr, int total, int N) {
    int i = blockIdx.x * blockDim.x + threadIdx.x;
    if (i < total) csr[i] = N;
}

__global__ void fill_csr(const int* __restrict__ ei, const unsigned* __restrict__ rowptr,
                         unsigned* __restrict__ cursor, int* __restrict__ csr, int E) {
    int e = blockIdx.x * blockDim.x + threadIdx.x;
    if (e >= E) return;
    size_t st = ei_stride(ei);
    int s = ei[(size_t)e * st];
    int d = ei[((size_t)E + e) * st];
    unsigned pos = atomicAdd(&cursor[d], 1u);
    csr[rowptr[d] + pos] = s;
}

// Prep: wT_hi/lo[n*K + k] = split_bf16(W[k*NOUT + n])   (one-time, tiny)
__global__ void split_wT(const float* __restrict__ W, unsigned short* __restrict__ wT_hi,
                         unsigned short* __restrict__ wT_lo, int K, int NOUT) {
    int idx = blockIdx.x * blockDim.x + threadIdx.x;
    if (idx >= K * NOUT) return;
    int k = idx / NOUT, n = idx % NOUT;
    unsigned short h, l;
    split_bf16(W[idx], h, l);
    wT_hi[(size_t)n * K + k] = h;
    wT_lo[(size_t)n * K + k] = l;
}

// ---------------------------------------------------------------------------
// Yb[r, NOUT_] = bf16( scale[r] * (X[r,:] @ W) ), MFMA 16x16x32.
// Also zeroes the zero-node row (row nrows) from block 0.
// ---------------------------------------------------------------------------
template <int K_, int NOUT_, bool SPLITA>
__global__ __launch_bounds__(256)
void gemm_mfma(const void* __restrict__ Xv, const unsigned short* __restrict__ wT_hi,
               const unsigned short* __restrict__ wT_lo, const float* __restrict__ scale,
               unsigned short* __restrict__ Yb, int nrows) {
    constexpr int BM = 64, BK = 32, NKT = K_ / BK;
    constexpr int CT = NOUT_ / 64;            // col-tiles per wave
    constexpr int LDW = BK + 8;               // 80B row stride (16B multiple)
    constexpr int WPT = NOUT_ / 32;           // ushort4/thread/half for W staging

    __shared__ __attribute__((aligned(16))) unsigned short xs_hi[BM][LDW];
    __shared__ __attribute__((aligned(16))) unsigned short xs_lo[SPLITA ? BM : 1][SPLITA ? LDW : 1];
    __shared__ __attribute__((aligned(16))) unsigned short ws_hi[NOUT_][LDW];
    __shared__ __attribute__((aligned(16))) unsigned short ws_lo[NOUT_][LDW];

    const int t = threadIdx.x;
    const int wave = t >> 6, lane = t & 63;
    const int m16 = lane & 15, kg = lane >> 4;
    const int row0 = blockIdx.x * BM;
    const int n0 = wave * (16 * CT);

    // zero-node row for padded gathers
    if (blockIdx.x == 0 && t < NOUT_ / 8) {
        us8 z = (us8)0;
        *(us8*)&Yb[(size_t)nrows * NOUT_ + t * 8] = z;
    }

    const float* Xf = (const float*)Xv;
    const unsigned short* Xb = (const unsigned short*)Xv;

    f32x4 acc[4][CT];
#pragma unroll
    for (int r = 0; r < 4; ++r)
#pragma unroll
        for (int c = 0; c < CT; ++c) acc[r][c] = {0.f, 0.f, 0.f, 0.f};

    float4 xpre[2];
    us8 xpre_b;
    ushort4 wpre_h[WPT], wpre_l[WPT];

    if constexpr (SPLITA) {
#pragma unroll
        for (int i = 0; i < 2; ++i) {
            int idx = t + i * 256;
            int r = idx >> 3, c4 = idx & 7;
            int gr = row0 + r;
            xpre[i] = (gr < nrows) ? *(const float4*)&Xf[(size_t)gr * K_ + c4 * 4]
                                   : make_float4(0.f, 0.f, 0.f, 0.f);
        }
    } else {
        int r = t >> 2, c8 = t & 3;
        int gr = row0 + r;
        xpre_b = (gr < nrows) ? *(const us8*)&Xb[(size_t)gr * K_ + c8 * 8] : (us8)0;
    }
#pragma unroll
    for (int i = 0; i < WPT; ++i) {
        int idx = t + i * 256;
        int n = idx >> 3, c4 = idx & 7;
        wpre_h[i] = *(const ushort4*)&wT_hi[(size_t)n * K_ + c4 * 4];
        wpre_l[i] = *(const ushort4*)&wT_lo[(size_t)n * K_ + c4 * 4];
    }

    for (int kb = 0; kb < NKT; ++kb) {
        if constexpr (SPLITA) {
#pragma unroll
            for (int i = 0; i < 2; ++i) {
                int idx = t + i * 256;
                int r = idx >> 3, c4 = idx & 7;
                ushort4 h, l;
                split4(xpre[i], h, l);
                *(ushort4*)&xs_hi[r][c4 * 4] = h;
                *(ushort4*)&xs_lo[r][c4 * 4] = l;
            }
        } else {
            int r = t >> 2, c8 = t & 3;
            *(us8*)&xs_hi[r][c8 * 8] = xpre_b;
        }
#pragma unroll
        for (int i = 0; i < WPT; ++i) {
            int idx = t + i * 256;
            int n = idx >> 3, c4 = idx & 7;
            *(ushort4*)&ws_hi[n][c4 * 4] = wpre_h[i];
            *(ushort4*)&ws_lo[n][c4 * 4] = wpre_l[i];
        }
        __syncthreads();

        if (kb + 1 < NKT) {
            const int koff = (kb + 1) * BK;
            if constexpr (SPLITA) {
#pragma unroll
                for (int i = 0; i < 2; ++i) {
                    int idx = t + i * 256;
                    int r = idx >> 3, c4 = idx & 7;
                    int gr = row0 + r;
                    xpre[i] = (gr < nrows) ? *(const float4*)&Xf[(size_t)gr * K_ + koff + c4 * 4]
                                           : make_float4(0.f, 0.f, 0.f, 0.f);
                }
            } else {
                int r = t >> 2, c8 = t & 3;
                int gr = row0 + r;
                xpre_b = (gr < nrows) ? *(const us8*)&Xb[(size_t)gr * K_ + koff + c8 * 8] : (us8)0;
            }
#pragma unroll
            for (int i = 0; i < WPT; ++i) {
                int idx = t + i * 256;
                int n = idx >> 3, c4 = idx & 7;
                wpre_h[i] = *(const ushort4*)&wT_hi[(size_t)n * K_ + koff + c4 * 4];
                wpre_l[i] = *(const ushort4*)&wT_lo[(size_t)n * K_ + koff + c4 * 4];
            }
        }

        bf16x8 bh[CT], bl[CT];
#pragma unroll
        for (int c = 0; c < CT; ++c) {
            bh[c] = *(const bf16x8*)&ws_hi[n0 + c * 16 + m16][kg * 8];
            bl[c] = *(const bf16x8*)&ws_lo[n0 + c * 16 + m16][kg * 8];
        }
#pragma unroll
        for (int r = 0; r < 4; ++r) {
            bf16x8 ah = *(const bf16x8*)&xs_hi[r * 16 + m16][kg * 8];
            if constexpr (SPLITA) {
                bf16x8 al = *(const bf16x8*)&xs_lo[r * 16 + m16][kg * 8];
#pragma unroll
                for (int c = 0; c < CT; ++c) {
                    acc[r][c] = __builtin_amdgcn_mfma_f32_16x16x32_bf16(ah, bh[c], acc[r][c], 0, 0, 0);
                    acc[r][c] = __builtin_amdgcn_mfma_f32_16x16x32_bf16(ah, bl[c], acc[r][c], 0, 0, 0);
                    acc[r][c] = __builtin_amdgcn_mfma_f32_16x16x32_bf16(al, bh[c], acc[r][c], 0, 0, 0);
                }
            } else {
#pragma unroll
                for (int c = 0; c < CT; ++c) {
                    acc[r][c] = __builtin_amdgcn_mfma_f32_16x16x32_bf16(ah, bh[c], acc[r][c], 0, 0, 0);
                    acc[r][c] = __builtin_amdgcn_mfma_f32_16x16x32_bf16(ah, bl[c], acc[r][c], 0, 0, 0);
                }
            }
        }
        __syncthreads();
    }

#pragma unroll
    for (int r = 0; r < 4; ++r) {
#pragma unroll
        for (int j = 0; j < 4; ++j) {
            int gr = row0 + r * 16 + kg * 4 + j;
            if (gr < nrows) {
                float s = scale[gr];
#pragma unroll
                for (int c = 0; c < CT; ++c)
                    Yb[(size_t)gr * NOUT_ + n0 + c * 16 + m16] = bf16_rn(acc[r][c][j] * s);
            }
        }
    }
}

// ---------------------------------------------------------------------------
// Gather layer 1 (F=128, bf16 in/out, relu+dropout fused). 8-deep batches.
// ---------------------------------------------------------------------------
__global__ __launch_bounds__(256)
void gather_drop(const unsigned* __restrict__ hs /*bf16x2*/, const int* __restrict__ csr,
                 const unsigned* __restrict__ rowptr, const float* __restrict__ dinv,
                 const float* __restrict__ bias, unsigned* __restrict__ outb /*bf16x2*/,
                 int N) {
    const int node = blockIdx.x * 4 + (threadIdx.x >> 6);
    if (node >= N) return;
    const int lane = threadIdx.x & 63;
    const unsigned beg = rowptr[node];
    const unsigned end = rowptr[node + 1];   // (end-beg) % 8 == 0, pads -> row N (zeros)
    const float dn = dinv[node];

    unsigned v = hs[(size_t)node * 64 + lane];
    float ax = __uint_as_float(v << 16);
    float ay = __uint_as_float(v & 0xffff0000u);
    for (unsigned k = beg; k < end; k += 8) {
        int j[8];
#pragma unroll
        for (int u = 0; u < 8; ++u) j[u] = csr[k + u];
        unsigned w[8];
#pragma unroll
        for (int u = 0; u < 8; ++u) w[u] = hs[(size_t)j[u] * 64 + lane];
#pragma unroll
        for (int u = 0; u < 8; ++u) {
            ax += __uint_as_float(w[u] << 16);
            ay += __uint_as_float(w[u] & 0xffff0000u);
        }
    }
    const int f0 = 2 * lane;
    float o0 = fmaxf(dn * ax + bias[f0], 0.0f);
    float o1 = fmaxf(dn * ay + bias[f0 + 1], 0.0f);
    unsigned base = (unsigned)node * 128u + (unsigned)f0;
    o0 = dropout_keep(base) ? 2.0f * o0 : 0.0f;
    o1 = dropout_keep(base + 1u) ? 2.0f * o1 : 0.0f;
    outb[(size_t)node * 64 + lane] =
        (unsigned)bf16_rn(o0) | ((unsigned)bf16_rn(o1) << 16);
}

// ---------------------------------------------------------------------------
// Gather layer 2 (F=64, bf16 in, f32 out). 8-deep batches.
// ---------------------------------------------------------------------------
__global__ __launch_bounds__(256)
void gather_out(const unsigned short* __restrict__ hs /*bf16*/, const int* __restrict__ csr,
                const unsigned* __restrict__ rowptr, const float* __restrict__ dinv,
                const float* __restrict__ bias, float* __restrict__ outp, int N) {
    const int node = blockIdx.x * 4 + (threadIdx.x >> 6);
    if (node >= N) return;
    const int lane = threadIdx.x & 63;
    const unsigned beg = rowptr[node];
    const unsigned end = rowptr[node + 1];
    const float dn = dinv[node];

    float acc = __uint_as_float(((unsigned)hs[(size_t)node * 64 + lane]) << 16);
    for (unsigned k = beg; k < end; k += 8) {
        int j[8];
#pragma unroll
        for (int u = 0; u < 8; ++u) j[u] = csr[k + u];
        unsigned short w[8];
#pragma unroll
        for (int u = 0; u < 8; ++u) w[u] = hs[(size_t)j[u] * 64 + lane];
#pragma unroll
        for (int u = 0; u < 8; ++u) acc += __uint_as_float(((unsigned)w[u]) << 16);
    }
    outp[(size_t)node * 64 + lane] = dn * acc + bias[lane];
}

extern "C" void kernel_launch(void* const* d_in, const int* in_sizes, int n_in,
                              void* d_out, int out_size, void* d_ws, size_t ws_size,
                              hipStream_t stream) {
    const float* x  = (const float*)d_in[0];
    const int*   ei = (const int*)d_in[1];
    const float* W1 = (const float*)d_in[2];
    const float* b1 = (const float*)d_in[3];
    const float* W2 = (const float*)d_in[4];
    const float* b2 = (const float*)d_in[5];
    float* out = (float*)d_out;

    const int Fdim = 256, Hdim = 128, Cdim = 64;
    const int N = in_sizes[0] / Fdim;   // 50000
    const int E = in_sizes[1] / 2;      // 800000
    const int CSR_CAP = E + 7 * N;      // padded-slot upper bound
    const int NB = (N + 255) / 256;     // scan blocks (196)

    // workspace: wT1_hi|lo (256*128 us ea) | wT2_hi|lo (128*64 us ea) |
    //   buffA[(N+1)*128] bf16 | buffB[N*128] bf16 |
    //   deg[N] | cursor[N] | dinv[N] | rowptr[N+1] | blockSums[NB] | csr[CSR_CAP]
    unsigned short* wT1_hi = (unsigned short*)d_ws;
    unsigned short* wT1_lo = wT1_hi + 256 * 128;
    unsigned short* wT2_hi = wT1_lo + 256 * 128;
    unsigned short* wT2_lo = wT2_hi + 128 * 64;
    unsigned short* buffA  = wT2_lo + 128 * 64;
    unsigned short* buffB  = buffA + (size_t)(N + 1) * Hdim;
    unsigned* deg    = (unsigned*)(buffB + (size_t)N * Hdim);
    unsigned* cursor = deg + N;
    float*    dinv   = (float*)(cursor + N);
    unsigned* rowptr = (unsigned*)(dinv + N);
    unsigned* blockSums = rowptr + (N + 1);
    int*      csr    = (int*)(blockSums + NB);

    hipMemsetAsync(deg, 0, 2 * (size_t)N * sizeof(unsigned), stream);

    count_deg<<<(E + 255) / 256, 256, 0, stream>>>(ei, deg, E);
    fill_pad<<<(CSR_CAP + 255) / 256, 256, 0, stream>>>(csr, CSR_CAP, N);
    scan_phase1<<<NB, 256, 0, stream>>>(deg, blockSums, dinv, N);
    scan_phase2<<<1, 1024, 0, stream>>>(blockSums, NB);
    scan_phase3<<<NB, 256, 0, stream>>>(deg, blockSums, rowptr, N);
    fill_csr<<<(E + 255) / 256, 256, 0, stream>>>(ei, rowptr, cursor, csr, E);

    split_wT<<<(256 * 128 + 255) / 256, 256, 0, stream>>>(W1, wT1_hi, wT1_lo, 256, 128);
    split_wT<<<(128 * 64 + 255) / 256, 256, 0, stream>>>(W2, wT2_hi, wT2_lo, 128, 64);

    // layer 1
    gemm_mfma<256, 128, true><<<(N + 63) / 64, 256, 0, stream>>>(x, wT1_hi, wT1_lo, dinv, buffA, N);
    gather_drop<<<(N + 3) / 4, 256, 0, stream>>>((const unsigned*)buffA, csr, rowptr, dinv, b1,
                                                 (unsigned*)buffB, N);

    // layer 2
    gemm_mfma<128, 64, false><<<(N + 63) / 64, 256, 0, stream>>>(buffB, wT2_hi, wT2_lo, dinv, buffA, N);
    gather_out<<<(N + 3) / 4, 256, 0, stream>>>(buffA, csr, rowptr, dinv, b2, out, N);
}

// Round 9
// 246.800 us; speedup vs baseline: 3.2015x; 1.1676x over previous
//
#include <hip/hip_runtime.h>

// ---------------------------------------------------------------------------
// GCN 2-layer forward, CSR-gather formulation:
//   hs = dinv ⊙ (X @ W)   (GEMM epilogue scale, stored bf16)
//   out[i] = dinv[i]*(hs[i] + Σ_{j∈in(i)} hs[j]) + b
// GEMM1: split-bf16 MFMA (3 MFMA). GEMM2: bf16 A, split W (2 MFMA).
// CSR build: count pass captures each edge's slot (aux = atomic return),
// place pass is atomic-free; pad slots (to mult-of-8, zero-node N) written in
// scan_phase3. 8-deep branch-free gather batches.
// Dropout mask = JAX threefry2x32, key(42), partitionable fold (o0^o1), p=0.5.
//   (verified rounds 3-8)
// ---------------------------------------------------------------------------

typedef __attribute__((ext_vector_type(8))) short bf16x8;          // MFMA A/B
typedef __attribute__((ext_vector_type(4))) float f32x4;           // MFMA C/D
typedef __attribute__((ext_vector_type(8))) unsigned short us8;

__device__ __forceinline__ unsigned tf_rotl(unsigned x, int d) {
    return (x << d) | (x >> (32 - d));
}

__device__ __forceinline__ bool dropout_keep(unsigned flat_idx) {
    const unsigned K0 = 0u, K1 = 42u;
    const unsigned K2 = K0 ^ K1 ^ 0x1BD11BDAu;
    unsigned x0 = 0u, x1 = flat_idx;
    x0 += K0; x1 += K1;
#define TF_R(r) { x0 += x1; x1 = tf_rotl(x1, (r)); x1 ^= x0; }
    TF_R(13) TF_R(15) TF_R(26) TF_R(6)
    x0 += K1; x1 += K2 + 1u;
    TF_R(17) TF_R(29) TF_R(16) TF_R(24)
    x0 += K2; x1 += K0 + 2u;
    TF_R(13) TF_R(15) TF_R(26) TF_R(6)
    x0 += K0; x1 += K1 + 3u;
    TF_R(17) TF_R(29) TF_R(16) TF_R(24)
    x0 += K1; x1 += K2 + 4u;
    TF_R(13) TF_R(15) TF_R(26) TF_R(6)
    x0 += K2; x1 += K0 + 5u;
#undef TF_R
    return (((x0 ^ x1) >> 31) & 1u) == 0u;   // fold bits1^bits2, keep if < 2^31
}

// ---- bf16 helpers ----------------------------------------------------------
__device__ __forceinline__ unsigned short bf16_rn(float x) {
    unsigned u = __float_as_uint(x);
    unsigned r = u + 0x7FFFu + ((u >> 16) & 1u);
    return (unsigned short)(r >> 16);
}
__device__ __forceinline__ void split_bf16(float x, unsigned short& h, unsigned short& l) {
    h = bf16_rn(x);
    float fh = __uint_as_float(((unsigned)h) << 16);
    l = bf16_rn(x - fh);
}
__device__ __forceinline__ void split4(float4 v, ushort4& h, ushort4& l) {
    unsigned short h0, h1, h2, h3, l0, l1, l2, l3;
    split_bf16(v.x, h0, l0); split_bf16(v.y, h1, l1);
    split_bf16(v.z, h2, l2); split_bf16(v.w, h3, l3);
    h = make_ushort4(h0, h1, h2, h3);
    l = make_ushort4(l0, l1, l2, l3);
}

// int32 vs int64 edge-index autodetect (values < 50000 -> i64 hi words are 0).
__device__ __forceinline__ int ei_stride(const int* __restrict__ ei) {
    bool i64 = true;
#pragma unroll
    for (int k = 1; k <= 15; k += 2) i64 = i64 && (ei[k] == 0);
    return i64 ? 2 : 1;
}

// pass 1: deg count + per-edge slot capture (atomic return)
__global__ void count_slot(const int* __restrict__ ei, unsigned* __restrict__ deg,
                           unsigned* __restrict__ aux, int E) {
    int e = blockIdx.x * blockDim.x + threadIdx.x;
    if (e >= E) return;
    size_t st = ei_stride(ei);
    aux[e] = atomicAdd(&deg[ei[((size_t)E + e) * st]], 1u);
}

// ---------------------------------------------------------------------------
// 3-phase device-wide exclusive scan of padded degrees (pad8), fused dinv;
// phase 3 also writes the pad slots (zero-node N) into csr.
// ---------------------------------------------------------------------------
__global__ __launch_bounds__(256)
void scan_phase1(const unsigned* __restrict__ deg, unsigned* __restrict__ blockSums,
                 float* __restrict__ dinv, int N) {
    const int i = blockIdx.x * 256 + threadIdx.x;
    const int lane = threadIdx.x & 63, wave = threadIdx.x >> 6;
    unsigned v = 0;
    if (i < N) {
        unsigned d = deg[i];
        v = (d + 7u) & ~7u;
        dinv[i] = rsqrtf((float)(d + 1u));   // +1 = self loop
    }
    unsigned s = v;
#pragma unroll
    for (int o = 32; o > 0; o >>= 1) s += __shfl_down(s, o, 64);
    __shared__ unsigned ws[4];
    if (lane == 0) ws[wave] = s;
    __syncthreads();
    if (threadIdx.x == 0)
        blockSums[blockIdx.x] = ws[0] + ws[1] + ws[2] + ws[3];
}

__global__ __launch_bounds__(1024)
void scan_phase2(unsigned* __restrict__ blockSums, int nb) {
    __shared__ unsigned s[1024];
    const int t = threadIdx.x;
    unsigned v = (t < nb) ? blockSums[t] : 0u;
    s[t] = v;
    __syncthreads();
    for (int off = 1; off < 1024; off <<= 1) {
        unsigned u = (t >= off) ? s[t - off] : 0u;
        __syncthreads();
        s[t] += u;
        __syncthreads();
    }
    if (t < nb) blockSums[t] = s[t] - v;   // exclusive
}

__global__ __launch_bounds__(256)
void scan_phase3(const unsigned* __restrict__ deg, const unsigned* __restrict__ blockSums,
                 unsigned* __restrict__ rowptr, int* __restrict__ csr, int N) {
    const int i = blockIdx.x * 256 + threadIdx.x;
    const int t = threadIdx.x;
    unsigned d = 0, v = 0;
    if (i < N) {
        d = deg[i];
        v = (d + 7u) & ~7u;
    }
    __shared__ unsigned s[256];
    s[t] = v;
    __syncthreads();
    for (int off = 1; off < 256; off <<= 1) {
        unsigned u = (t >= off) ? s[t - off] : 0u;
        __syncthreads();
        s[t] += u;
        __syncthreads();
    }
    const unsigned incl = s[t];
    const unsigned off0 = blockSums[blockIdx.x];
    if (i < N) {
        const unsigned rp = off0 + incl - v;
        rowptr[i] = rp;
        if (i == N - 1) rowptr[N] = off0 + incl;
        for (unsigned u = d; u < v; ++u) csr[rp + u] = N;   // pad -> zero-node
    }
}

// pass 2: atomic-free placement
__global__ void place_edges(const int* __restrict__ ei, const unsigned* __restrict__ rowptr,
                            const unsigned* __restrict__ aux, int* __restrict__ csr, int E) {
    int e = blockIdx.x * blockDim.x + threadIdx.x;
    if (e >= E) return;
    size_t st = ei_stride(ei);
    int s = ei[(size_t)e * st];
    int d = ei[((size_t)E + e) * st];
    csr[rowptr[d] + aux[e]] = s;
}

// Prep: both weights split/transposed in one launch.
// W1: [256,128] -> wT1[n*256+k]; W2: [128,64] -> wT2[n*128+k]
__global__ void split_both(const float* __restrict__ W1, const float* __restrict__ W2,
                           unsigned short* __restrict__ wT1_hi, unsigned short* __restrict__ wT1_lo,
                           unsigned short* __restrict__ wT2_hi, unsigned short* __restrict__ wT2_lo) {
    int idx = blockIdx.x * blockDim.x + threadIdx.x;
    unsigned short h, l;
    if (idx < 256 * 128) {
        int k = idx / 128, n = idx % 128;
        split_bf16(W1[idx], h, l);
        wT1_hi[(size_t)n * 256 + k] = h;
        wT1_lo[(size_t)n * 256 + k] = l;
    } else if (idx < 256 * 128 + 128 * 64) {
        int j = idx - 256 * 128;
        int k = j / 64, n = j % 64;
        split_bf16(W2[j], h, l);
        wT2_hi[(size_t)n * 128 + k] = h;
        wT2_lo[(size_t)n * 128 + k] = l;
    }
}

// ---------------------------------------------------------------------------
// Yb[r, NOUT_] = bf16( scale[r] * (X[r,:] @ W) ), MFMA 16x16x32.
// Also zeroes the zero-node row (row nrows) from block 0.
// ---------------------------------------------------------------------------
template <int K_, int NOUT_, bool SPLITA>
__global__ __launch_bounds__(256)
void gemm_mfma(const void* __restrict__ Xv, const unsigned short* __restrict__ wT_hi,
               const unsigned short* __restrict__ wT_lo, const float* __restrict__ scale,
               unsigned short* __restrict__ Yb, int nrows) {
    constexpr int BM = 64, BK = 32, NKT = K_ / BK;
    constexpr int CT = NOUT_ / 64;            // col-tiles per wave
    constexpr int LDW = BK + 8;               // 80B row stride (16B multiple)
    constexpr int WPT = NOUT_ / 32;           // ushort4/thread/half for W staging

    __shared__ __attribute__((aligned(16))) unsigned short xs_hi[BM][LDW];
    __shared__ __attribute__((aligned(16))) unsigned short xs_lo[SPLITA ? BM : 1][SPLITA ? LDW : 1];
    __shared__ __attribute__((aligned(16))) unsigned short ws_hi[NOUT_][LDW];
    __shared__ __attribute__((aligned(16))) unsigned short ws_lo[NOUT_][LDW];

    const int t = threadIdx.x;
    const int wave = t >> 6, lane = t & 63;
    const int m16 = lane & 15, kg = lane >> 4;
    const int row0 = blockIdx.x * BM;
    const int n0 = wave * (16 * CT);

    // zero-node row for padded gathers
    if (blockIdx.x == 0 && t < NOUT_ / 8) {
        us8 z = (us8)0;
        *(us8*)&Yb[(size_t)nrows * NOUT_ + t * 8] = z;
    }

    const float* Xf = (const float*)Xv;
    const unsigned short* Xb = (const unsigned short*)Xv;

    f32x4 acc[4][CT];
#pragma unroll
    for (int r = 0; r < 4; ++r)
#pragma unroll
        for (int c = 0; c < CT; ++c) acc[r][c] = {0.f, 0.f, 0.f, 0.f};

    float4 xpre[2];
    us8 xpre_b;
    ushort4 wpre_h[WPT], wpre_l[WPT];

    if constexpr (SPLITA) {
#pragma unroll
        for (int i = 0; i < 2; ++i) {
            int idx = t + i * 256;
            int r = idx >> 3, c4 = idx & 7;
            int gr = row0 + r;
            xpre[i] = (gr < nrows) ? *(const float4*)&Xf[(size_t)gr * K_ + c4 * 4]
                                   : make_float4(0.f, 0.f, 0.f, 0.f);
        }
    } else {
        int r = t >> 2, c8 = t & 3;
        int gr = row0 + r;
        xpre_b = (gr < nrows) ? *(const us8*)&Xb[(size_t)gr * K_ + c8 * 8] : (us8)0;
    }
#pragma unroll
    for (int i = 0; i < WPT; ++i) {
        int idx = t + i * 256;
        int n = idx >> 3, c4 = idx & 7;
        wpre_h[i] = *(const ushort4*)&wT_hi[(size_t)n * K_ + c4 * 4];
        wpre_l[i] = *(const ushort4*)&wT_lo[(size_t)n * K_ + c4 * 4];
    }

    for (int kb = 0; kb < NKT; ++kb) {
        if constexpr (SPLITA) {
#pragma unroll
            for (int i = 0; i < 2; ++i) {
                int idx = t + i * 256;
                int r = idx >> 3, c4 = idx & 7;
                ushort4 h, l;
                split4(xpre[i], h, l);
                *(ushort4*)&xs_hi[r][c4 * 4] = h;
                *(ushort4*)&xs_lo[r][c4 * 4] = l;
            }
        } else {
            int r = t >> 2, c8 = t & 3;
            *(us8*)&xs_hi[r][c8 * 8] = xpre_b;
        }
#pragma unroll
        for (int i = 0; i < WPT; ++i) {
            int idx = t + i * 256;
            int n = idx >> 3, c4 = idx & 7;
            *(ushort4*)&ws_hi[n][c4 * 4] = wpre_h[i];
            *(ushort4*)&ws_lo[n][c4 * 4] = wpre_l[i];
        }
        __syncthreads();

        if (kb + 1 < NKT) {
            const int koff = (kb + 1) * BK;
            if constexpr (SPLITA) {
#pragma unroll
                for (int i = 0; i < 2; ++i) {
                    int idx = t + i * 256;
                    int r = idx >> 3, c4 = idx & 7;
                    int gr = row0 + r;
                    xpre[i] = (gr < nrows) ? *(const float4*)&Xf[(size_t)gr * K_ + koff + c4 * 4]
                                           : make_float4(0.f, 0.f, 0.f, 0.f);
                }
            } else {
                int r = t >> 2, c8 = t & 3;
                int gr = row0 + r;
                xpre_b = (gr < nrows) ? *(const us8*)&Xb[(size_t)gr * K_ + koff + c8 * 8] : (us8)0;
            }
#pragma unroll
            for (int i = 0; i < WPT; ++i) {
                int idx = t + i * 256;
                int n = idx >> 3, c4 = idx & 7;
                wpre_h[i] = *(const ushort4*)&wT_hi[(size_t)n * K_ + koff + c4 * 4];
                wpre_l[i] = *(const ushort4*)&wT_lo[(size_t)n * K_ + koff + c4 * 4];
            }
        }

        bf16x8 bh[CT], bl[CT];
#pragma unroll
        for (int c = 0; c < CT; ++c) {
            bh[c] = *(const bf16x8*)&ws_hi[n0 + c * 16 + m16][kg * 8];
            bl[c] = *(const bf16x8*)&ws_lo[n0 + c * 16 + m16][kg * 8];
        }
#pragma unroll
        for (int r = 0; r < 4; ++r) {
            bf16x8 ah = *(const bf16x8*)&xs_hi[r * 16 + m16][kg * 8];
            if constexpr (SPLITA) {
                bf16x8 al = *(const bf16x8*)&xs_lo[r * 16 + m16][kg * 8];
#pragma unroll
                for (int c = 0; c < CT; ++c) {
                    acc[r][c] = __builtin_amdgcn_mfma_f32_16x16x32_bf16(ah, bh[c], acc[r][c], 0, 0, 0);
                    acc[r][c] = __builtin_amdgcn_mfma_f32_16x16x32_bf16(ah, bl[c], acc[r][c], 0, 0, 0);
                    acc[r][c] = __builtin_amdgcn_mfma_f32_16x16x32_bf16(al, bh[c], acc[r][c], 0, 0, 0);
                }
            } else {
#pragma unroll
                for (int c = 0; c < CT; ++c) {
                    acc[r][c] = __builtin_amdgcn_mfma_f32_16x16x32_bf16(ah, bh[c], acc[r][c], 0, 0, 0);
                    acc[r][c] = __builtin_amdgcn_mfma_f32_16x16x32_bf16(ah, bl[c], acc[r][c], 0, 0, 0);
                }
            }
        }
        __syncthreads();
    }

#pragma unroll
    for (int r = 0; r < 4; ++r) {
#pragma unroll
        for (int j = 0; j < 4; ++j) {
            int gr = row0 + r * 16 + kg * 4 + j;
            if (gr < nrows) {
                float s = scale[gr];
#pragma unroll
                for (int c = 0; c < CT; ++c)
                    Yb[(size_t)gr * NOUT_ + n0 + c * 16 + m16] = bf16_rn(acc[r][c][j] * s);
            }
        }
    }
}

// ---------------------------------------------------------------------------
// Gather layer 1 (F=128, bf16 in/out, relu+dropout fused). 8-deep batches.
// ---------------------------------------------------------------------------
__global__ __launch_bounds__(256)
void gather_drop(const unsigned* __restrict__ hs /*bf16x2*/, const int* __restrict__ csr,
                 const unsigned* __restrict__ rowptr, const float* __restrict__ dinv,
                 const float* __restrict__ bias, unsigned* __restrict__ outb /*bf16x2*/,
                 int N) {
    const int node = blockIdx.x * 4 + (threadIdx.x >> 6);
    if (node >= N) return;
    const int lane = threadIdx.x & 63;
    const unsigned beg = rowptr[node];
    const unsigned end = rowptr[node + 1];   // (end-beg) % 8 == 0, pads -> row N (zeros)
    const float dn = dinv[node];

    unsigned v = hs[(size_t)node * 64 + lane];
    float ax = __uint_as_float(v << 16);
    float ay = __uint_as_float(v & 0xffff0000u);
    for (unsigned k = beg; k < end; k += 8) {
        int j[8];
#pragma unroll
        for (int u = 0; u < 8; ++u) j[u] = csr[k + u];
        unsigned w[8];
#pragma unroll
        for (int u = 0; u < 8; ++u) w[u] = hs[(size_t)j[u] * 64 + lane];
#pragma unroll
        for (int u = 0; u < 8; ++u) {
            ax += __uint_as_float(w[u] << 16);
            ay += __uint_as_float(w[u] & 0xffff0000u);
        }
    }
    const int f0 = 2 * lane;
    float o0 = fmaxf(dn * ax + bias[f0], 0.0f);
    float o1 = fmaxf(dn * ay + bias[f0 + 1], 0.0f);
    unsigned base = (unsigned)node * 128u + (unsigned)f0;
    o0 = dropout_keep(base) ? 2.0f * o0 : 0.0f;
    o1 = dropout_keep(base + 1u) ? 2.0f * o1 : 0.0f;
    outb[(size_t)node * 64 + lane] =
        (unsigned)bf16_rn(o0) | ((unsigned)bf16_rn(o1) << 16);
}

// ---------------------------------------------------------------------------
// Gather layer 2 (F=64, bf16 in, f32 out). 8-deep batches.
// ---------------------------------------------------------------------------
__global__ __launch_bounds__(256)
void gather_out(const unsigned short* __restrict__ hs /*bf16*/, const int* __restrict__ csr,
                const unsigned* __restrict__ rowptr, const float* __restrict__ dinv,
                const float* __restrict__ bias, float* __restrict__ outp, int N) {
    const int node = blockIdx.x * 4 + (threadIdx.x >> 6);
    if (node >= N) return;
    const int lane = threadIdx.x & 63;
    const unsigned beg = rowptr[node];
    const unsigned end = rowptr[node + 1];
    const float dn = dinv[node];

    float acc = __uint_as_float(((unsigned)hs[(size_t)node * 64 + lane]) << 16);
    for (unsigned k = beg; k < end; k += 8) {
        int j[8];
#pragma unroll
        for (int u = 0; u < 8; ++u) j[u] = csr[k + u];
        unsigned short w[8];
#pragma unroll
        for (int u = 0; u < 8; ++u) w[u] = hs[(size_t)j[u] * 64 + lane];
#pragma unroll
        for (int u = 0; u < 8; ++u) acc += __uint_as_float(((unsigned)w[u]) << 16);
    }
    outp[(size_t)node * 64 + lane] = dn * acc + bias[lane];
}

extern "C" void kernel_launch(void* const* d_in, const int* in_sizes, int n_in,
                              void* d_out, int out_size, void* d_ws, size_t ws_size,
                              hipStream_t stream) {
    const float* x  = (const float*)d_in[0];
    const int*   ei = (const int*)d_in[1];
    const float* W1 = (const float*)d_in[2];
    const float* b1 = (const float*)d_in[3];
    const float* W2 = (const float*)d_in[4];
    const float* b2 = (const float*)d_in[5];
    float* out = (float*)d_out;

    const int Fdim = 256, Hdim = 128, Cdim = 64;
    const int N = in_sizes[0] / Fdim;   // 50000
    const int E = in_sizes[1] / 2;      // 800000
    const int CSR_CAP = E + 7 * N;      // padded-slot upper bound
    const int NB = (N + 255) / 256;     // scan blocks (196)

    // workspace: wT1_hi|lo (256*128 us ea) | wT2_hi|lo (128*64 us ea) |
    //   buffA[(N+1)*128] bf16 | buffB[N*128] bf16 |
    //   deg[N] | dinv[N] | rowptr[N+1] | blockSums[NB] | aux[E] | csr[CSR_CAP]
    unsigned short* wT1_hi = (unsigned short*)d_ws;
    unsigned short* wT1_lo = wT1_hi + 256 * 128;
    unsigned short* wT2_hi = wT1_lo + 256 * 128;
    unsigned short* wT2_lo = wT2_hi + 128 * 64;
    unsigned short* buffA  = wT2_lo + 128 * 64;
    unsigned short* buffB  = buffA + (size_t)(N + 1) * Hdim;
    unsigned* deg    = (unsigned*)(buffB + (size_t)N * Hdim);
    float*    dinv   = (float*)(deg + N);
    unsigned* rowptr = (unsigned*)(dinv + N);
    unsigned* blockSums = rowptr + (N + 1);
    unsigned* aux    = blockSums + NB;
    int*      csr    = (int*)(aux + E);

    hipMemsetAsync(deg, 0, (size_t)N * sizeof(unsigned), stream);

    count_slot<<<(E + 255) / 256, 256, 0, stream>>>(ei, deg, aux, E);
    scan_phase1<<<NB, 256, 0, stream>>>(deg, blockSums, dinv, N);
    scan_phase2<<<1, 1024, 0, stream>>>(blockSums, NB);
    scan_phase3<<<NB, 256, 0, stream>>>(deg, blockSums, rowptr, csr, N);
    place_edges<<<(E + 255) / 256, 256, 0, stream>>>(ei, rowptr, aux, csr, E);

    split_both<<<(256 * 128 + 128 * 64 + 255) / 256, 256, 0, stream>>>(
        W1, W2, wT1_hi, wT1_lo, wT2_hi, wT2_lo);

    // layer 1
    gemm_mfma<256, 128, true><<<(N + 63) / 64, 256, 0, stream>>>(x, wT1_hi, wT1_lo, dinv, buffA, N);
    gather_drop<<<(N + 3) / 4, 256, 0, stream>>>((const unsigned*)buffA, csr, rowptr, dinv, b1,
                                                 (unsigned*)buffB, N);

    // layer 2
    gemm_mfma<128, 64, false><<<(N + 63) / 64, 256, 0, stream>>>(buffB, wT2_hi, wT2_lo, dinv, buffA, N);
    gather_out<<<(N + 3) / 4, 256, 0, stream>>>(buffA, csr, rowptr, dinv, b2, out, N);
}